// Round 1
// baseline (2491.454 us; speedup 1.0000x reference)
//
#include <hip/hip_runtime.h>
#include <hip/hip_bf16.h>
#include <math.h>

typedef __attribute__((ext_vector_type(8))) short short8;
typedef __attribute__((ext_vector_type(8))) __bf16 bf16x8;
typedef __attribute__((ext_vector_type(4))) float f32x4;

#define DEVI static __device__ __forceinline__

DEVI short f2bf(float f) {
  union { float f; unsigned u; } v; v.f = f;
  unsigned r = v.u + 0x7fffu + ((v.u >> 16) & 1u);
  return (short)(r >> 16);
}

// ---------------------------------------------------------------------------
// Generic bf16-MFMA GEMM: C[m,n] = epi( scale * sum_k A[m,k]*B(k,n) + bias[n] )
// BMODE 0: B stored [N,K] row-major (weights W[out,in], K^T, token_emb)
// BMODE 1: B stored [K,N] row-major (basis_A[n], Vv)
// EPI 0: plain store, 1: exact GELU, 2: residual add (C += val)
// colmul (nullable): multiply by per-column factor (gate for `fin`)
// Batched via blockIdx.z: z1=z/zdiv, z2=z%zdiv, offsets z1*s1+z2*s2 per tensor.
// Requires M%64==0, N%64==0, K%32==0 (true for every call here).
// ---------------------------------------------------------------------------
template<int BMODE, int EPI>
__global__ __launch_bounds__(256) void gemm_kernel(
    const float* __restrict__ A, const float* __restrict__ B, float* __restrict__ C,
    const float* __restrict__ bias, const float* __restrict__ colmul,
    int M, int N, int K, int lda, int ldb, int ldc,
    long sA1, long sA2, long sB1, long sB2, long sC1, long sC2, int zdiv,
    float scale)
{
  __shared__ short As[64][40];
  __shared__ short Bs[64][40];
  {
    int z = blockIdx.z; int z1 = z / zdiv, z2 = z - z1 * zdiv;
    A += (long)z1 * sA1 + (long)z2 * sA2;
    B += (long)z1 * sB1 + (long)z2 * sB2;
    C += (long)z1 * sC1 + (long)z2 * sC2;
  }
  const int n0 = blockIdx.x * 64, m0 = blockIdx.y * 64;
  const int tid = threadIdx.x;
  const int lane = tid & 63, wv = tid >> 6;
  const int wm = wv >> 1, wn = wv & 1;
  const int l16 = lane & 15, lq = lane >> 4;
  const int am = tid >> 2, akc = (tid & 3) << 3;   // A/BT loader: row, k-chunk
  const int bk = tid >> 3, bnc = (tid & 7) << 3;   // BN loader: k-row, n-chunk
  const f32x4 zf = {0.f, 0.f, 0.f, 0.f};
  f32x4 acc00 = zf, acc01 = zf, acc10 = zf, acc11 = zf;

  for (int k0 = 0; k0 < K; k0 += 32) {
    {
      const float* ap = A + (long)(m0 + am) * lda + (k0 + akc);
      float4 u = *(const float4*)ap;
      float4 v = *(const float4*)(ap + 4);
      short8 s;
      s[0]=f2bf(u.x); s[1]=f2bf(u.y); s[2]=f2bf(u.z); s[3]=f2bf(u.w);
      s[4]=f2bf(v.x); s[5]=f2bf(v.y); s[6]=f2bf(v.z); s[7]=f2bf(v.w);
      *(short8*)&As[am][akc] = s;
    }
    if (BMODE == 0) {
      const float* bp = B + (long)(n0 + am) * ldb + (k0 + akc);
      float4 u = *(const float4*)bp;
      float4 v = *(const float4*)(bp + 4);
      short8 s;
      s[0]=f2bf(u.x); s[1]=f2bf(u.y); s[2]=f2bf(u.z); s[3]=f2bf(u.w);
      s[4]=f2bf(v.x); s[5]=f2bf(v.y); s[6]=f2bf(v.z); s[7]=f2bf(v.w);
      *(short8*)&Bs[am][akc] = s;
    } else {
      const float* bp = B + (long)(k0 + bk) * ldb + (n0 + bnc);
      float4 u = *(const float4*)bp;
      float4 v = *(const float4*)(bp + 4);
      Bs[bnc + 0][bk] = f2bf(u.x);
      Bs[bnc + 1][bk] = f2bf(u.y);
      Bs[bnc + 2][bk] = f2bf(u.z);
      Bs[bnc + 3][bk] = f2bf(u.w);
      Bs[bnc + 4][bk] = f2bf(v.x);
      Bs[bnc + 5][bk] = f2bf(v.y);
      Bs[bnc + 6][bk] = f2bf(v.z);
      Bs[bnc + 7][bk] = f2bf(v.w);
    }
    __syncthreads();
    bf16x8 a0 = __builtin_bit_cast(bf16x8, *(const short8*)&As[wm*32 + l16][lq*8]);
    bf16x8 a1 = __builtin_bit_cast(bf16x8, *(const short8*)&As[wm*32 + 16 + l16][lq*8]);
    bf16x8 b0 = __builtin_bit_cast(bf16x8, *(const short8*)&Bs[wn*32 + l16][lq*8]);
    bf16x8 b1 = __builtin_bit_cast(bf16x8, *(const short8*)&Bs[wn*32 + 16 + l16][lq*8]);
    acc00 = __builtin_amdgcn_mfma_f32_16x16x32_bf16(a0, b0, acc00, 0, 0, 0);
    acc01 = __builtin_amdgcn_mfma_f32_16x16x32_bf16(a0, b1, acc01, 0, 0, 0);
    acc10 = __builtin_amdgcn_mfma_f32_16x16x32_bf16(a1, b0, acc10, 0, 0, 0);
    acc11 = __builtin_amdgcn_mfma_f32_16x16x32_bf16(a1, b1, acc11, 0, 0, 0);
    __syncthreads();
  }

  // Epilogue. C/D layout (verified): col = lane&15, row = (lane>>4)*4 + reg.
  auto store_tile = [&](f32x4 a, int tm, int tn) {
    int col = n0 + wn*32 + tn*16 + l16;
    float cb = bias ? bias[col] : 0.f;
    float cm = colmul ? colmul[col] : 1.f;
    int rbase = m0 + wm*32 + tm*16 + lq*4;
#pragma unroll
    for (int j = 0; j < 4; j++) {
      float val = a[j] * scale + cb;
      val *= cm;
      long idx = (long)(rbase + j) * ldc + col;
      if (EPI == 1)      { val = 0.5f * val * (1.f + erff(val * 0.70710678118654752f)); C[idx] = val; }
      else if (EPI == 2) { C[idx] += val; }
      else               { C[idx] = val; }
    }
  };
  store_tile(acc00, 0, 0); store_tile(acc01, 0, 1);
  store_tile(acc10, 1, 0); store_tile(acc11, 1, 1);
}

// ---------------------------------------------------------------------------
// Elementwise / small kernels
// ---------------------------------------------------------------------------

// x[t,:] = token_emb[ids[t],:] + pos_emb[t%1024,:]   (one float4 per thread)
__global__ __launch_bounds__(256) void embed_kernel(
    const int* __restrict__ ids, const float* __restrict__ tok,
    const float* __restrict__ pos, float* __restrict__ x)
{
  int i = blockIdx.x * 256 + threadIdx.x;   // < 4096*128
  int t = i >> 7, c = (i & 127) * 4;
  int sp = t & 1023;
  int id = ids[t];
  float4 a = *(const float4*)(tok + (long)id * 512 + c);
  float4 b = *(const float4*)(pos + (long)sp * 512 + c);
  float4 r; r.x=a.x+b.x; r.y=a.y+b.y; r.z=a.z+b.z; r.w=a.w+b.w;
  *(float4*)(x + (long)t * 512 + c) = r;
}

// LayerNorm over D=512: one wave per row, 4 rows/block.
__global__ __launch_bounds__(256) void ln_kernel(
    const float* __restrict__ in, float* __restrict__ out,
    const float* __restrict__ gam, const float* __restrict__ bet)
{
  int row = blockIdx.x * 4 + (threadIdx.x >> 6);
  int lane = threadIdx.x & 63;
  const float* p = in + (long)row * 512;
  float4 v0 = *(const float4*)(p + lane * 4);
  float4 v1 = *(const float4*)(p + 256 + lane * 4);
  float s = v0.x+v0.y+v0.z+v0.w + v1.x+v1.y+v1.z+v1.w;
#pragma unroll
  for (int o = 32; o; o >>= 1) s += __shfl_xor(s, o);
  float mean = s * (1.f/512.f);
  float d0=v0.x-mean, d1=v0.y-mean, d2=v0.z-mean, d3=v0.w-mean;
  float e0=v1.x-mean, e1=v1.y-mean, e2=v1.z-mean, e3=v1.w-mean;
  float q = d0*d0+d1*d1+d2*d2+d3*d3 + e0*e0+e1*e1+e2*e2+e3*e3;
#pragma unroll
  for (int o = 32; o; o >>= 1) q += __shfl_xor(q, o);
  float inv = rsqrtf(q * (1.f/512.f) + 1e-5f);
  float4 g0 = *(const float4*)(gam + lane*4);
  float4 g1 = *(const float4*)(gam + 256 + lane*4);
  float4 b0 = *(const float4*)(bet + lane*4);
  float4 b1 = *(const float4*)(bet + 256 + lane*4);
  float4 o0, o1;
  o0.x = d0*inv*g0.x + b0.x; o0.y = d1*inv*g0.y + b0.y;
  o0.z = d2*inv*g0.z + b0.z; o0.w = d3*inv*g0.w + b0.w;
  o1.x = e0*inv*g1.x + b1.x; o1.y = e1*inv*g1.y + b1.y;
  o1.z = e2*inv*g1.z + b1.z; o1.w = e3*inv*g1.w + b1.w;
  *(float4*)(out + (long)row*512 + lane*4) = o0;
  *(float4*)(out + (long)row*512 + 256 + lane*4) = o1;
}

// Causal softmax in place over [32*1024, 1024]; masked entries written as 0.
__global__ __launch_bounds__(256) void softmax_kernel(float* __restrict__ sc)
{
  long gw = (long)blockIdx.x * 4 + (threadIdx.x >> 6);
  int lane = threadIdx.x & 63;
  int s = (int)(gw & 1023);
  float* row = sc + gw * 1024;
  float v[16];
  float m = -1e30f;
#pragma unroll
  for (int i = 0; i < 16; i++) {
    int t = lane + i * 64;
    v[i] = (t <= s) ? row[t] : -1e30f;
    m = fmaxf(m, v[i]);
  }
#pragma unroll
  for (int o = 32; o; o >>= 1) m = fmaxf(m, __shfl_xor(m, o));
  float sum = 0.f;
#pragma unroll
  for (int i = 0; i < 16; i++) {
    int t = lane + i * 64;
    v[i] = (t <= s) ? expf(v[i] - m) : 0.f;
    sum += v[i];
  }
#pragma unroll
  for (int o = 32; o; o >>= 1) sum += __shfl_xor(sum, o);
  float inv = 1.f / sum;
#pragma unroll
  for (int i = 0; i < 16; i++) row[lane + i*64] = v[i] * inv;
}

// Per (l,n): rec_sm = softmax(recipe row), emb_sem = rec_sm @ basis_emb,
// gate = sigmoid(mean_h ctx_pat / S)  [summary==1/S identically]
__global__ __launch_bounds__(64) void precompute_kernel(
    const float* __restrict__ recipe, const float* __restrict__ basis_emb,
    const float* __restrict__ ctx_pat, float* __restrict__ rec_sm,
    float* __restrict__ emb_sem, float* __restrict__ gate)
{
  int ln = blockIdx.x;          // l*256 + n
  int lane = threadIdx.x;
  const float* r = recipe + (long)ln * 32;
  float rv[32];
  float m = -1e30f;
#pragma unroll
  for (int j = 0; j < 32; j++) { rv[j] = r[j]; m = fmaxf(m, rv[j]); }
  float sum = 0.f;
#pragma unroll
  for (int j = 0; j < 32; j++) { rv[j] = expf(rv[j] - m); sum += rv[j]; }
  float inv = 1.f / sum;
#pragma unroll
  for (int j = 0; j < 32; j++) rv[j] *= inv;
  if (lane < 32) rec_sm[(long)ln * 32 + lane] = rv[lane];
#pragma unroll
  for (int cc = 0; cc < 8; cc++) {
    int c = lane + cc * 64;
    float acc = 0.f;
#pragma unroll
    for (int j = 0; j < 32; j++) acc += rv[j] * basis_emb[j * 512 + c];
    emb_sem[(long)ln * 512 + c] = acc;
  }
  if (lane == 0) {
    float sh = 0.f;
#pragma unroll
    for (int h = 0; h < 8; h++) sh += ctx_pat[(long)ln * 8 + h];
    gate[ln] = 1.f / (1.f + expf(-sh * (1.f/1024.f)));
  }
}

// Per token: top-8 of fin[256], softmax weights, token_recipe[32] = sum w_k*rec_sm[idx_k]
__global__ __launch_bounds__(64) void topk_kernel(
    const float* __restrict__ fin, const float* __restrict__ rec_sm_l,
    float* __restrict__ tr)
{
  int t = blockIdx.x;
  int lane = threadIdx.x;
  const float* f = fin + (long)t * 256;
  float v0 = f[lane], v1 = f[lane+64], v2 = f[lane+128], v3 = f[lane+192];
  int i0 = lane, i1 = lane+64, i2 = lane+128, i3 = lane+192;
  float topv[8]; int topi[8];
#pragma unroll
  for (int it = 0; it < 8; it++) {
    float bm = v0; int bi = i0;
    if (v1 > bm || (v1 == bm && i1 < bi)) { bm = v1; bi = i1; }
    if (v2 > bm || (v2 == bm && i2 < bi)) { bm = v2; bi = i2; }
    if (v3 > bm || (v3 == bm && i3 < bi)) { bm = v3; bi = i3; }
#pragma unroll
    for (int o = 32; o; o >>= 1) {
      float om = __shfl_xor(bm, o);
      int oi = __shfl_xor(bi, o);
      if (om > bm || (om == bm && oi < bi)) { bm = om; bi = oi; }
    }
    topv[it] = bm; topi[it] = bi;
    if (i0 == bi) v0 = -1e30f;
    if (i1 == bi) v1 = -1e30f;
    if (i2 == bi) v2 = -1e30f;
    if (i3 == bi) v3 = -1e30f;
  }
  float w[8], wsum = 0.f;
#pragma unroll
  for (int k = 0; k < 8; k++) { w[k] = expf(topv[k] - topv[0]); wsum += w[k]; }
  float inv = 1.f / wsum;
  if (lane < 32) {
    float acc = 0.f;
#pragma unroll
    for (int k = 0; k < 8; k++)
      acc += (w[k] * inv) * rec_sm_l[(long)topi[k] * 32 + lane];
    tr[(long)t * 32 + lane] = acc;
  }
}

// v_sem[t,r] = sum_n tr[t,n] * xA[t,n,r]; one wave per token (r = lane, lane+64)
__global__ __launch_bounds__(256) void vsem_reduce_kernel(
    const float* __restrict__ XA, const float* __restrict__ tr,
    float* __restrict__ out)
{
  int t = blockIdx.x * 4 + (threadIdx.x >> 6);
  int lane = threadIdx.x & 63;
  const float* xa = XA + (long)t * 4096;
  const float* tt = tr + (long)t * 32;
  float a0 = 0.f, a1 = 0.f;
#pragma unroll
  for (int n = 0; n < 32; n++) {
    float w = tt[n];
    a0 += w * xa[n*128 + lane];
    a1 += w * xa[n*128 + 64 + lane];
  }
  out[(long)t * 128 + lane] = a0;
  out[(long)t * 128 + 64 + lane] = a1;
}

// ---------------------------------------------------------------------------
// Host side
// ---------------------------------------------------------------------------
static void gemm(hipStream_t st, int bmode, int epi,
                 const float* A, const float* B, float* C,
                 const float* bias, const float* colmul,
                 int M, int N, int K, int lda, int ldb, int ldc,
                 int nbatch, long sA1, long sA2, long sB1, long sB2,
                 long sC1, long sC2, int zdiv, float scale)
{
  dim3 g(N/64, M/64, nbatch), blk(256);
#define GL(BM,EP) gemm_kernel<BM,EP><<<g,blk,0,st>>>(A,B,C,bias,colmul,M,N,K,lda,ldb,ldc,sA1,sA2,sB1,sB2,sC1,sC2,zdiv,scale)
  if (bmode == 0) {
    if (epi == 0) GL(0,0); else if (epi == 1) GL(0,1); else GL(0,2);
  } else {
    if (epi == 0) GL(1,0); else if (epi == 1) GL(1,1); else GL(1,2);
  }
#undef GL
}

extern "C" void kernel_launch(void* const* d_in, const int* in_sizes, int n_in,
                              void* d_out, int out_size, void* d_ws, size_t ws_size,
                              hipStream_t stream) {
  (void)in_sizes; (void)n_in; (void)out_size; (void)ws_size;
  const int*   ids       = (const int*)  d_in[0];
  const float* token_emb = (const float*)d_in[1];
  const float* pos_emb   = (const float*)d_in[2];
  const float* basis_A   = (const float*)d_in[3];
  const float* basis_emb = (const float*)d_in[4];
  const float* q_w  = (const float*)d_in[5];
  const float* q_b  = (const float*)d_in[6];
  const float* k_w  = (const float*)d_in[7];
  const float* k_b  = (const float*)d_in[8];
  const float* ao_w = (const float*)d_in[9];
  const float* ao_b = (const float*)d_in[10];
  const float* recipe  = (const float*)d_in[11];
  const float* ctx_pat = (const float*)d_in[12];
  const float* vout_w  = (const float*)d_in[13];
  const float* vout_b  = (const float*)d_in[14];
  const float* up_w    = (const float*)d_in[15];
  const float* up_b    = (const float*)d_in[16];
  const float* down_w  = (const float*)d_in[17];
  const float* down_b  = (const float*)d_in[18];
  const float* ln1_s = (const float*)d_in[19];
  const float* ln1_b = (const float*)d_in[20];
  const float* ln2_s = (const float*)d_in[21];
  const float* ln2_b = (const float*)d_in[22];
  const float* lnf_s = (const float*)d_in[23];
  const float* lnf_b = (const float*)d_in[24];
  float* out = (float*)d_out;

  // ws layout (floats); total ~14.85M floats (~59 MB)
  float* ws = (float*)d_ws;
  float* x      = ws;               // [4096,512]
  float* nrm    = x      + 2097152; // [4096,512]
  float* qb     = nrm    + 2097152; // [4096,512]
  float* kb     = qb     + 2097152; // [4096,512]
  float* vvb    = kb     + 2097152; // [4096,512]
  float* aob    = vvb    + 2097152; // [4096,512]
  float* finb   = aob    + 2097152; // [4096,256]
  float* trb    = finb   + 1048576; // [4096,32]
  float* vsem   = trb    + 131072;  // [4096,128]
  float* embsem = vsem   + 524288;  // [4,256,512]
  float* recsm  = embsem + 524288;  // [4,256,32]
  float* gate   = recsm  + 32768;   // [4,256]

  // Big transient buffers live in d_out (524 MB; disjoint lifetimes per layer):
  float* XA = out;   // [4096,32,128]  = 67 MB
  float* SC = out;   // [32,1024,1024] = 134 MB
  float* HF = out;   // [4096,2048]    = 33 MB

  embed_kernel<<<2048, 256, 0, stream>>>(ids, token_emb, pos_emb, x);
  precompute_kernel<<<1024, 64, 0, stream>>>(recipe, basis_emb, ctx_pat, recsm, embsem, gate);

  for (int l = 0; l < 4; l++) {
    ln_kernel<<<1024, 256, 0, stream>>>(x, nrm, ln1_s + l*512, ln1_b + l*512);

    // fin = (nrm @ emb_sem[l]^T) * gate[l]
    gemm(stream, 0, 0, nrm, embsem + (long)l*131072, finb, nullptr, gate + l*256,
         4096, 256, 512, 512, 512, 256, 1, 0,0,0,0,0,0, 1, 1.f);
    topk_kernel<<<4096, 64, 0, stream>>>(finb, recsm + (long)l*8192, trb);

    // xA[t,n,r] = nrm @ basis_A[n]   (batched over n=0..31, BN layout)
    gemm(stream, 1, 0, nrm, basis_A, XA, nullptr, nullptr,
         4096, 128, 512, 512, 128, 4096, 32, 0,0, 0,65536, 0,128, 32, 1.f);
    vsem_reduce_kernel<<<1024, 256, 0, stream>>>(XA, trb, vsem);

    // Vv = v_sem @ vout_w^T + vout_b   -> [4096,512]
    gemm(stream, 0, 0, vsem, vout_w + (long)l*65536, vvb, vout_b + l*512, nullptr,
         4096, 512, 128, 128, 128, 512, 1, 0,0,0,0,0,0, 1, 1.f);

    // Q, K projections -> [4096,512]
    gemm(stream, 0, 0, nrm, q_w + (long)l*262144, qb, q_b + l*512, nullptr,
         4096, 512, 512, 512, 512, 512, 1, 0,0,0,0,0,0, 1, 1.f);
    gemm(stream, 0, 0, nrm, k_w + (long)l*262144, kb, k_b + l*512, nullptr,
         4096, 512, 512, 512, 512, 512, 1, 0,0,0,0,0,0, 1, 1.f);

    // scores[b,h] = 0.125 * Q[b,h] @ K[b,h]^T   (batched over 32 (b,h))
    gemm(stream, 0, 0, qb, kb, SC, nullptr, nullptr,
         1024, 1024, 64, 512, 512, 1024, 32,
         524288, 64, 524288, 64, 8388608, 1048576, 8, 0.125f);
    softmax_kernel<<<8192, 256, 0, stream>>>(SC);

    // ao[b,h] = attn[b,h] @ Vv[b,h]   (BN layout on Vv slice)
    gemm(stream, 1, 0, SC, vvb, aob, nullptr, nullptr,
         1024, 64, 1024, 1024, 512, 512, 32,
         8388608, 1048576, 524288, 64, 524288, 64, 8, 1.f);

    // x += ao @ ao_w^T + ao_b
    gemm(stream, 0, 2, aob, ao_w + (long)l*262144, x, ao_b + l*512, nullptr,
         4096, 512, 512, 512, 512, 512, 1, 0,0,0,0,0,0, 1, 1.f);

    // FFN
    ln_kernel<<<1024, 256, 0, stream>>>(x, nrm, ln2_s + l*512, ln2_b + l*512);
    gemm(stream, 0, 1, nrm, up_w + (long)l*1048576, HF, up_b + l*2048, nullptr,
         4096, 2048, 512, 512, 512, 2048, 1, 0,0,0,0,0,0, 1, 1.f);
    gemm(stream, 0, 2, HF, down_w + (long)l*1048576, x, down_b + l*512, nullptr,
         4096, 512, 2048, 2048, 2048, 512, 1, 0,0,0,0,0,0, 1, 1.f);
  }

  // Final LN + tied head
  ln_kernel<<<1024, 256, 0, stream>>>(x, nrm, lnf_s, lnf_b);
  gemm(stream, 0, 0, nrm, token_emb, out, nullptr, nullptr,
       4096, 32000, 512, 512, 512, 32000, 1, 0,0,0,0,0,0, 1, 1.f);
}

// Round 2
// 1634.921 us; speedup vs baseline: 1.5239x; 1.5239x over previous
//
#include <hip/hip_runtime.h>
#include <hip/hip_bf16.h>
#include <math.h>

typedef __attribute__((ext_vector_type(8))) short short8;
typedef __attribute__((ext_vector_type(4))) short short4v;
typedef __attribute__((ext_vector_type(8))) __bf16 bf16x8;
typedef __attribute__((ext_vector_type(4))) float f32x4;
typedef unsigned short ushort;

#define DEVI static __device__ __forceinline__

DEVI ushort f2bf(float f) {
  union { float f; unsigned u; } v; v.f = f;
  unsigned r = v.u + 0x7fffu + ((v.u >> 16) & 1u);
  return (ushort)(r >> 16);
}
DEVI float bf2f(ushort h) {
  union { unsigned u; float f; } v; v.u = (unsigned)h << 16; return v.f;
}
DEVI void gload16(const void* g, void* l) {
  __builtin_amdgcn_global_load_lds((const __attribute__((address_space(1))) void*)g,
                                   (__attribute__((address_space(3))) void*)l, 16, 0, 0);
}

// ---------------------------------------------------------------------------
// 128x128 bf16 MFMA GEMM (m97 structure): A [M,K] bf16, B [N,K] bf16 (B^T),
// BK=32, 4 waves (2x2 of 64x64), global_load_lds staging, XCD swizzle.
// EPI: 0=f32 store, 1=bf16 store, 2=GELU->bf16, 3=f32 residual add, 4=f32 NT store
// ---------------------------------------------------------------------------
template<int EPI>
__global__ __launch_bounds__(256) void gemm128(
    const ushort* __restrict__ A, const ushort* __restrict__ B,
    void* __restrict__ Cv, const float* __restrict__ bias,
    const float* __restrict__ colmul,
    int K, int lda, int ldb, int ldc,
    long sA1, long sA2, long sB1, long sB2, long sC1, long sC2,
    int zdiv, float scale, int causal)
{
  __shared__ ushort As[4096];   // [128][32] linear
  __shared__ ushort Bs[4096];
  const int z = blockIdx.z; const int z1 = z / zdiv, z2 = z - z1 * zdiv;
  A += (long)z1 * sA1 + (long)z2 * sA2;
  B += (long)z1 * sB1 + (long)z2 * sB2;
  const long coff = (long)z1 * sC1 + (long)z2 * sC2;

  // bijective XCD swizzle over the (x,y) plane (m204)
  const int gx = gridDim.x;
  const int nwg = gx * gridDim.y;
  const int orig = blockIdx.y * gx + blockIdx.x;
  const int q = nwg >> 3, r = nwg & 7;
  const int xcd = orig & 7, sidx = orig >> 3;
  const int wg = (xcd < r ? xcd * (q + 1) : r * (q + 1) + (xcd - r) * q) + sidx;
  const int n0 = (wg % gx) * 128, m0 = (wg / gx) * 128;
  if (causal && n0 > m0 + 127) return;

  const int tid = threadIdx.x;
  const int arow = tid >> 2, acolb = (tid & 3) << 4;   // staging row / byte col
  const int lane = tid & 63, wv = tid >> 6;
  const int wm = wv >> 1, wn = wv & 1;
  const int l16 = lane & 15, lq = lane >> 4;

  f32x4 acc[4][4];
#pragma unroll
  for (int i = 0; i < 4; i++)
#pragma unroll
    for (int j = 0; j < 4; j++) acc[i][j] = (f32x4){0.f, 0.f, 0.f, 0.f};

  const char* Ab = (const char*)(A + (long)(m0 + arow) * lda) + acolb;
  const char* Bb = (const char*)(B + (long)(n0 + arow) * ldb) + acolb;
  const long a64 = (long)64 * lda * 2, b64 = (long)64 * ldb * 2;
  char* la = (char*)As + tid * 16;
  char* lb = (char*)Bs + tid * 16;

  for (int k0 = 0; k0 < K; k0 += 32) {
    const char* ap = Ab + (long)k0 * 2;
    const char* bp = Bb + (long)k0 * 2;
    gload16(ap, la);
    gload16(ap + a64, la + 4096);
    gload16(bp, lb);
    gload16(bp + b64, lb + 4096);
    __syncthreads();
    bf16x8 af[4], bfr[4];
#pragma unroll
    for (int i = 0; i < 4; i++) {
      af[i]  = __builtin_bit_cast(bf16x8, *(const short8*)&As[(wm*64 + i*16 + l16)*32 + lq*8]);
      bfr[i] = __builtin_bit_cast(bf16x8, *(const short8*)&Bs[(wn*64 + i*16 + l16)*32 + lq*8]);
    }
#pragma unroll
    for (int i = 0; i < 4; i++)
#pragma unroll
      for (int j = 0; j < 4; j++)
        acc[i][j] = __builtin_amdgcn_mfma_f32_16x16x32_bf16(af[i], bfr[j], acc[i][j], 0, 0, 0);
    __syncthreads();
  }

  float* Cf = (float*)Cv;
  ushort* Ch = (ushort*)Cv;
#pragma unroll
  for (int i = 0; i < 4; i++) {
    const int row0 = m0 + wm*64 + i*16 + lq*4;
#pragma unroll
    for (int j = 0; j < 4; j++) {
      const int col = n0 + wn*64 + j*16 + l16;
      const float cb = bias ? bias[col] : 0.f;
      const float cm = colmul ? colmul[col] : 1.f;
#pragma unroll
      for (int t = 0; t < 4; t++) {
        float val = acc[i][j][t] * scale + cb;
        val *= cm;
        const long idx = coff + (long)(row0 + t) * ldc + col;
        if (EPI == 0)      Cf[idx] = val;
        else if (EPI == 1) Ch[idx] = f2bf(val);
        else if (EPI == 2) { val = 0.5f * val * (1.f + erff(val * 0.70710678118654752f)); Ch[idx] = f2bf(val); }
        else if (EPI == 3) Cf[idx] += val;
        else               __builtin_nontemporal_store(val, Cf + idx);
      }
    }
  }
}

// ---------------------------------------------------------------------------
// 64x64 bf16 GEMM for attn@V: A [M,K] bf16, B [K,N] bf16, C bf16, causal klimit
// ---------------------------------------------------------------------------
__global__ __launch_bounds__(256) void av_kernel(
    const ushort* __restrict__ A, const ushort* __restrict__ B, ushort* __restrict__ C,
    int K, int lda, int ldb, int ldc,
    long sA1, long sA2, long sB1, long sB2, long sC1, long sC2, int zdiv, int causal)
{
  __shared__ ushort As[64][40];
  __shared__ ushort Bs[64][40];
  const int z = blockIdx.z, z1 = z / zdiv, z2 = z - z1 * zdiv;
  A += (long)z1 * sA1 + (long)z2 * sA2;
  B += (long)z1 * sB1 + (long)z2 * sB2;
  C += (long)z1 * sC1 + (long)z2 * sC2;
  const int n0 = blockIdx.x * 64, m0 = blockIdx.y * 64;
  const int tid = threadIdx.x;
  const int lane = tid & 63, wv = tid >> 6;
  const int wm = wv >> 1, wn = wv & 1;
  const int l16 = lane & 15, lq = lane >> 4;
  const int am = tid >> 2, akc = (tid & 3) << 3;
  const int bk = tid >> 3, bnc = (tid & 7) << 3;
  const f32x4 zf = {0.f, 0.f, 0.f, 0.f};
  f32x4 acc00 = zf, acc01 = zf, acc10 = zf, acc11 = zf;
  const int keff = causal ? ((K < m0 + 64) ? K : m0 + 64) : K;

  for (int k0 = 0; k0 < keff; k0 += 32) {
    *(short8*)&As[am][akc] = *(const short8*)(A + (long)(m0 + am) * lda + k0 + akc);
    {
      short8 s = *(const short8*)(B + (long)(k0 + bk) * ldb + n0 + bnc);
#pragma unroll
      for (int jj = 0; jj < 8; jj++) Bs[bnc + jj][bk] = (ushort)s[jj];
    }
    __syncthreads();
    bf16x8 a0 = __builtin_bit_cast(bf16x8, *(const short8*)&As[wm*32 + l16][lq*8]);
    bf16x8 a1 = __builtin_bit_cast(bf16x8, *(const short8*)&As[wm*32 + 16 + l16][lq*8]);
    bf16x8 b0 = __builtin_bit_cast(bf16x8, *(const short8*)&Bs[wn*32 + l16][lq*8]);
    bf16x8 b1 = __builtin_bit_cast(bf16x8, *(const short8*)&Bs[wn*32 + 16 + l16][lq*8]);
    acc00 = __builtin_amdgcn_mfma_f32_16x16x32_bf16(a0, b0, acc00, 0, 0, 0);
    acc01 = __builtin_amdgcn_mfma_f32_16x16x32_bf16(a0, b1, acc01, 0, 0, 0);
    acc10 = __builtin_amdgcn_mfma_f32_16x16x32_bf16(a1, b0, acc10, 0, 0, 0);
    acc11 = __builtin_amdgcn_mfma_f32_16x16x32_bf16(a1, b1, acc11, 0, 0, 0);
    __syncthreads();
  }
  auto stt = [&](f32x4 a, int tm, int tn) {
    int col = n0 + wn*32 + tn*16 + l16;
    int rbase = m0 + wm*32 + tm*16 + lq*4;
#pragma unroll
    for (int j = 0; j < 4; j++)
      C[(long)(rbase + j) * ldc + col] = f2bf(a[j]);
  };
  stt(acc00, 0, 0); stt(acc01, 0, 1); stt(acc10, 1, 0); stt(acc11, 1, 1);
}

// ---------------------------------------------------------------------------
// small kernels
// ---------------------------------------------------------------------------
__global__ __launch_bounds__(256) void cvt_bf16(const float* __restrict__ src, ushort* __restrict__ dst) {
  long i = ((long)blockIdx.x * 256 + threadIdx.x) * 8;
  float4 u = *(const float4*)(src + i), v = *(const float4*)(src + i + 4);
  short8 s;
  s[0]=(short)f2bf(u.x); s[1]=(short)f2bf(u.y); s[2]=(short)f2bf(u.z); s[3]=(short)f2bf(u.w);
  s[4]=(short)f2bf(v.x); s[5]=(short)f2bf(v.y); s[6]=(short)f2bf(v.z); s[7]=(short)f2bf(v.w);
  *(short8*)(dst + i) = s;
}

// basis_A [32][512][128] f32 -> basisAT [32][128][512] bf16
__global__ __launch_bounds__(256) void transpose_basisA(
    const float* __restrict__ src, ushort* __restrict__ dst)
{
  __shared__ ushort tile[64][132];
  const int n = blockIdx.x;
  const int d0 = blockIdx.y * 64;
  const int tid = threadIdx.x;
#pragma unroll
  for (int it = 0; it < 8; it++) {
    int d = it * 8 + (tid >> 5);
    int rr = (tid & 31) * 4;
    float4 v = *(const float4*)(src + ((long)n * 512 + d0 + d) * 128 + rr);
    tile[d][rr + 0] = f2bf(v.x);
    tile[d][rr + 1] = f2bf(v.y);
    tile[d][rr + 2] = f2bf(v.z);
    tile[d][rr + 3] = f2bf(v.w);
  }
  __syncthreads();
#pragma unroll
  for (int it = 0; it < 4; it++) {
    int rr = it * 32 + (tid >> 3);
    int dof = (tid & 7) * 8;
    short8 s;
#pragma unroll
    for (int j = 0; j < 8; j++) s[j] = (short)tile[dof + j][rr];
    *(short8*)(dst + ((long)n * 128 + rr) * 512 + d0 + dof) = s;
  }
}

__global__ __launch_bounds__(256) void embed_kernel(
    const int* __restrict__ ids, const float* __restrict__ tok,
    const float* __restrict__ pos, float* __restrict__ x)
{
  int i = blockIdx.x * 256 + threadIdx.x;
  int t = i >> 7, c = (i & 127) * 4;
  int sp = t & 1023;
  int id = ids[t];
  float4 a = *(const float4*)(tok + (long)id * 512 + c);
  float4 b = *(const float4*)(pos + (long)sp * 512 + c);
  float4 rr; rr.x=a.x+b.x; rr.y=a.y+b.y; rr.z=a.z+b.z; rr.w=a.w+b.w;
  *(float4*)(x + (long)t * 512 + c) = rr;
}

// LayerNorm over D=512, bf16 output
__global__ __launch_bounds__(256) void ln_kernel(
    const float* __restrict__ in, ushort* __restrict__ outh,
    const float* __restrict__ gam, const float* __restrict__ bet)
{
  int row = blockIdx.x * 4 + (threadIdx.x >> 6);
  int lane = threadIdx.x & 63;
  const float* p = in + (long)row * 512;
  float4 v0 = *(const float4*)(p + lane * 4);
  float4 v1 = *(const float4*)(p + 256 + lane * 4);
  float s = v0.x+v0.y+v0.z+v0.w + v1.x+v1.y+v1.z+v1.w;
#pragma unroll
  for (int o = 32; o; o >>= 1) s += __shfl_xor(s, o);
  float mean = s * (1.f/512.f);
  float d0=v0.x-mean, d1=v0.y-mean, d2=v0.z-mean, d3=v0.w-mean;
  float e0=v1.x-mean, e1=v1.y-mean, e2=v1.z-mean, e3=v1.w-mean;
  float qv = d0*d0+d1*d1+d2*d2+d3*d3 + e0*e0+e1*e1+e2*e2+e3*e3;
#pragma unroll
  for (int o = 32; o; o >>= 1) qv += __shfl_xor(qv, o);
  float inv = rsqrtf(qv * (1.f/512.f) + 1e-5f);
  float4 g0 = *(const float4*)(gam + lane*4);
  float4 g1 = *(const float4*)(gam + 256 + lane*4);
  float4 b0 = *(const float4*)(bet + lane*4);
  float4 b1 = *(const float4*)(bet + 256 + lane*4);
  short4v o0, o1;
  o0[0]=(short)f2bf(d0*inv*g0.x + b0.x); o0[1]=(short)f2bf(d1*inv*g0.y + b0.y);
  o0[2]=(short)f2bf(d2*inv*g0.z + b0.z); o0[3]=(short)f2bf(d3*inv*g0.w + b0.w);
  o1[0]=(short)f2bf(e0*inv*g1.x + b1.x); o1[1]=(short)f2bf(e1*inv*g1.y + b1.y);
  o1[2]=(short)f2bf(e2*inv*g1.z + b1.z); o1[3]=(short)f2bf(e3*inv*g1.w + b1.w);
  *(short4v*)(outh + (long)row*512 + lane*4) = o0;
  *(short4v*)(outh + (long)row*512 + 256 + lane*4) = o1;
}

// causal softmax: reads f32 scores (lower triangle only), writes bf16 attn (zeros above)
__global__ __launch_bounds__(256) void softmax_kernel(
    const float* __restrict__ sc, ushort* __restrict__ att)
{
  long gw = (long)blockIdx.x * 4 + (threadIdx.x >> 6);
  int lane = threadIdx.x & 63;
  int s = (int)(gw & 1023);
  const float* row = sc + gw * 1024;
  ushort* orow = att + gw * 1024;
  float v[16];
  float m = -1e30f;
#pragma unroll
  for (int i = 0; i < 16; i++) {
    int t = lane + i * 64;
    v[i] = (t <= s) ? row[t] : -1e30f;
    m = fmaxf(m, v[i]);
  }
#pragma unroll
  for (int o = 32; o; o >>= 1) m = fmaxf(m, __shfl_xor(m, o));
  float sum = 0.f;
#pragma unroll
  for (int i = 0; i < 16; i++) {
    int t = lane + i * 64;
    v[i] = (t <= s) ? expf(v[i] - m) : 0.f;
    sum += v[i];
  }
#pragma unroll
  for (int o = 32; o; o >>= 1) sum += __shfl_xor(sum, o);
  float inv = 1.f / sum;
#pragma unroll
  for (int i = 0; i < 16; i++) {
    int t = lane + i * 64;
    orow[t] = (t <= s) ? f2bf(v[i] * inv) : (ushort)0;
  }
}

// per (l,n): rec_sm=softmax(recipe), emb_sem(bf16)=rec_sm@basis_emb, gate=const
__global__ __launch_bounds__(64) void precompute_kernel(
    const float* __restrict__ recipe, const float* __restrict__ basis_emb,
    const float* __restrict__ ctx_pat, float* __restrict__ rec_sm,
    ushort* __restrict__ emb_sem, float* __restrict__ gate)
{
  int ln = blockIdx.x;
  int lane = threadIdx.x;
  const float* r = recipe + (long)ln * 32;
  float rv[32];
  float m = -1e30f;
#pragma unroll
  for (int j = 0; j < 32; j++) { rv[j] = r[j]; m = fmaxf(m, rv[j]); }
  float sum = 0.f;
#pragma unroll
  for (int j = 0; j < 32; j++) { rv[j] = expf(rv[j] - m); sum += rv[j]; }
  float inv = 1.f / sum;
#pragma unroll
  for (int j = 0; j < 32; j++) rv[j] *= inv;
  if (lane < 32) rec_sm[(long)ln * 32 + lane] = rv[lane];
#pragma unroll
  for (int cc = 0; cc < 8; cc++) {
    int c = lane + cc * 64;
    float acc = 0.f;
#pragma unroll
    for (int j = 0; j < 32; j++) acc += rv[j] * basis_emb[j * 512 + c];
    emb_sem[(long)ln * 512 + c] = f2bf(acc);
  }
  if (lane == 0) {
    float sh = 0.f;
#pragma unroll
    for (int h = 0; h < 8; h++) sh += ctx_pat[(long)ln * 8 + h];
    gate[ln] = 1.f / (1.f + expf(-sh * (1.f/1024.f)));
  }
}

__global__ __launch_bounds__(64) void topk_kernel(
    const float* __restrict__ fin, const float* __restrict__ rec_sm_l,
    float* __restrict__ tr)
{
  int t = blockIdx.x;
  int lane = threadIdx.x;
  const float* f = fin + (long)t * 256;
  float v0 = f[lane], v1 = f[lane+64], v2 = f[lane+128], v3 = f[lane+192];
  int i0 = lane, i1 = lane+64, i2 = lane+128, i3 = lane+192;
  float topv[8]; int topi[8];
#pragma unroll
  for (int it = 0; it < 8; it++) {
    float bm = v0; int bi = i0;
    if (v1 > bm || (v1 == bm && i1 < bi)) { bm = v1; bi = i1; }
    if (v2 > bm || (v2 == bm && i2 < bi)) { bm = v2; bi = i2; }
    if (v3 > bm || (v3 == bm && i3 < bi)) { bm = v3; bi = i3; }
#pragma unroll
    for (int o = 32; o; o >>= 1) {
      float om = __shfl_xor(bm, o);
      int oi = __shfl_xor(bi, o);
      if (om > bm || (om == bm && oi < bi)) { bm = om; bi = oi; }
    }
    topv[it] = bm; topi[it] = bi;
    if (i0 == bi) v0 = -1e30f;
    if (i1 == bi) v1 = -1e30f;
    if (i2 == bi) v2 = -1e30f;
    if (i3 == bi) v3 = -1e30f;
  }
  float w[8], wsum = 0.f;
#pragma unroll
  for (int k = 0; k < 8; k++) { w[k] = expf(topv[k] - topv[0]); wsum += w[k]; }
  float inv = 1.f / wsum;
  if (lane < 32) {
    float acc = 0.f;
#pragma unroll
    for (int k = 0; k < 8; k++)
      acc += (w[k] * inv) * rec_sm_l[(long)topi[k] * 32 + lane];
    tr[(long)t * 32 + lane] = acc;
  }
}

// v_sem[t,r] = sum_n tr[t,n] * XA_bf16[t,n,r] -> bf16
__global__ __launch_bounds__(256) void vsem_kernel(
    const ushort* __restrict__ XA, const float* __restrict__ tr,
    ushort* __restrict__ out)
{
  int t = blockIdx.x * 4 + (threadIdx.x >> 6);
  int lane = threadIdx.x & 63;
  const ushort* xa = XA + (long)t * 4096;
  const float* tt = tr + (long)t * 32;
  float a0 = 0.f, a1 = 0.f;
#pragma unroll
  for (int n = 0; n < 32; n++) {
    float w = tt[n];
    a0 += w * bf2f(xa[n*128 + lane]);
    a1 += w * bf2f(xa[n*128 + 64 + lane]);
  }
  out[(long)t * 128 + lane] = f2bf(a0);
  out[(long)t * 128 + 64 + lane] = f2bf(a1);
}

// ---------------------------------------------------------------------------
// host
// ---------------------------------------------------------------------------
static inline void g128(hipStream_t st, int epi,
                        const ushort* A, const ushort* B, void* C,
                        const float* bias, const float* colmul,
                        int M, int N, int K, int lda, int ldb, int ldc, int nb,
                        long sA1, long sA2, long sB1, long sB2, long sC1, long sC2,
                        int zdiv, float scale, int causal)
{
  dim3 g(N/128, M/128, nb), b(256);
#define GK(E) gemm128<E><<<g,b,0,st>>>(A,B,C,bias,colmul,K,lda,ldb,ldc,sA1,sA2,sB1,sB2,sC1,sC2,zdiv,scale,causal)
  switch (epi) {
    case 0: GK(0); break; case 1: GK(1); break; case 2: GK(2); break;
    case 3: GK(3); break; default: GK(4); break;
  }
#undef GK
}

extern "C" void kernel_launch(void* const* d_in, const int* in_sizes, int n_in,
                              void* d_out, int out_size, void* d_ws, size_t ws_size,
                              hipStream_t stream) {
  (void)in_sizes; (void)n_in; (void)out_size; (void)ws_size;
  const int*   ids       = (const int*)  d_in[0];
  const float* token_emb = (const float*)d_in[1];
  const float* pos_emb   = (const float*)d_in[2];
  const float* basis_A   = (const float*)d_in[3];
  const float* basis_emb = (const float*)d_in[4];
  const float* q_w  = (const float*)d_in[5];
  const float* q_b  = (const float*)d_in[6];
  const float* k_w  = (const float*)d_in[7];
  const float* k_b  = (const float*)d_in[8];
  const float* ao_w = (const float*)d_in[9];
  const float* ao_b = (const float*)d_in[10];
  const float* recipe  = (const float*)d_in[11];
  const float* ctx_pat = (const float*)d_in[12];
  const float* vout_w  = (const float*)d_in[13];
  const float* vout_b  = (const float*)d_in[14];
  const float* up_w    = (const float*)d_in[15];
  const float* up_b    = (const float*)d_in[16];
  const float* down_w  = (const float*)d_in[17];
  const float* down_b  = (const float*)d_in[18];
  const float* ln1_s = (const float*)d_in[19];
  const float* ln1_b = (const float*)d_in[20];
  const float* ln2_s = (const float*)d_in[21];
  const float* ln2_b = (const float*)d_in[22];
  const float* lnf_s = (const float*)d_in[23];
  const float* lnf_b = (const float*)d_in[24];
  float* out = (float*)d_out;

  // ws layout (~97 MB)
  float* ws    = (float*)d_ws;
  float* x     = ws;                 // [4096,512] f32
  float* finb  = x + 2097152;        // [4096,256] f32
  float* trb   = finb + 1048576;     // [4096,32] f32
  float* recsm = trb + 131072;       // [4,256,32] f32
  float* gate  = recsm + 32768;      // [4,256] f32
  ushort* u = (ushort*)(gate + 1024);
  ushort* nrmh    = u; u += 2097152;   // [4096,512]
  ushort* qh      = u; u += 2097152;
  ushort* kh      = u; u += 2097152;
  ushort* vvh     = u; u += 2097152;
  ushort* aoh     = u; u += 2097152;
  ushort* vsemh   = u; u += 524288;    // [4096,128]
  ushort* embsem  = u; u += 524288;    // [4,256,512]
  ushort* qwh     = u; u += 1048576;   // [4,512,512]
  ushort* kwh     = u; u += 1048576;
  ushort* aowh    = u; u += 1048576;
  ushort* voutwh  = u; u += 262144;    // [4,512,128]
  ushort* upwh    = u; u += 4194304;   // [4,2048,512]
  ushort* downwh  = u; u += 4194304;   // [4,512,2048]
  ushort* tembh   = u; u += 16384000;  // [32000,512]
  ushort* basisAT = u; u += 2097152;   // [32][128][512]

  // big transients in d_out (disjoint lifetimes)
  float*  SC  = out;                       // [32,1024,1024] f32 (lower tri)
  ushort* XAb = (ushort*)out;              // [4096,32,128] bf16
  ushort* HF  = (ushort*)out;              // [4096,2048] bf16
  ushort* ATT = (ushort*)out + 83886080;   // [32,1024,1024] bf16 @ byte 160MB

  // one-time conversions (run every launch; ~30 us)
  cvt_bf16<<<512, 256, 0, stream>>>(q_w, qwh);
  cvt_bf16<<<512, 256, 0, stream>>>(k_w, kwh);
  cvt_bf16<<<512, 256, 0, stream>>>(ao_w, aowh);
  cvt_bf16<<<128, 256, 0, stream>>>(vout_w, voutwh);
  cvt_bf16<<<2048, 256, 0, stream>>>(up_w, upwh);
  cvt_bf16<<<2048, 256, 0, stream>>>(down_w, downwh);
  cvt_bf16<<<8000, 256, 0, stream>>>(token_emb, tembh);
  transpose_basisA<<<dim3(32, 8), 256, 0, stream>>>(basis_A, basisAT);
  embed_kernel<<<2048, 256, 0, stream>>>(ids, token_emb, pos_emb, x);
  precompute_kernel<<<1024, 64, 0, stream>>>(recipe, basis_emb, ctx_pat, recsm, embsem, gate);

  for (int l = 0; l < 4; l++) {
    ln_kernel<<<1024, 256, 0, stream>>>(x, nrmh, ln1_s + l*512, ln1_b + l*512);
    // fin = (nrm @ emb_sem^T) * gate
    g128(stream, 0, nrmh, embsem + (long)l*131072, finb, nullptr, gate + l*256,
         4096, 256, 512, 512, 512, 256, 1, 0,0,0,0,0,0, 1, 1.f, 0);
    topk_kernel<<<4096, 64, 0, stream>>>(finb, recsm + (long)l*8192, trb);
    // xA (batched over n)
    g128(stream, 1, nrmh, basisAT, (void*)XAb, nullptr, nullptr,
         4096, 128, 512, 512, 512, 4096, 32, 0,0, 0,65536, 0,128, 32, 1.f, 0);
    vsem_kernel<<<1024, 256, 0, stream>>>(XAb, trb, vsemh);
    // Vv
    g128(stream, 1, vsemh, voutwh + (long)l*65536, vvh, vout_b + l*512, nullptr,
         4096, 512, 128, 128, 128, 512, 1, 0,0,0,0,0,0, 1, 1.f, 0);
    // Q, K
    g128(stream, 1, nrmh, qwh + (long)l*262144, qh, q_b + l*512, nullptr,
         4096, 512, 512, 512, 512, 512, 1, 0,0,0,0,0,0, 1, 1.f, 0);
    g128(stream, 1, nrmh, kwh + (long)l*262144, kh, k_b + l*512, nullptr,
         4096, 512, 512, 512, 512, 512, 1, 0,0,0,0,0,0, 1, 1.f, 0);
    // scores (causal-skipped blocks)
    g128(stream, 0, qh, kh, SC, nullptr, nullptr,
         1024, 1024, 64, 512, 512, 1024, 32,
         524288, 64, 524288, 64, 8388608, 1048576, 8, 0.125f, 1);
    softmax_kernel<<<8192, 256, 0, stream>>>(SC, ATT);
    // ao = attn @ Vv (causal k-limit)
    av_kernel<<<dim3(1, 16, 32), 256, 0, stream>>>(ATT, vvh, aoh,
         1024, 1024, 512, 512, 8388608, 1048576, 524288, 64, 524288, 64, 8, 1);
    // x += ao @ ao_w^T + b
    g128(stream, 3, aoh, aowh + (long)l*262144, x, ao_b + l*512, nullptr,
         4096, 512, 512, 512, 512, 512, 1, 0,0,0,0,0,0, 1, 1.f, 0);
    // FFN
    ln_kernel<<<1024, 256, 0, stream>>>(x, nrmh, ln2_s + l*512, ln2_b + l*512);
    g128(stream, 2, nrmh, upwh + (long)l*1048576, (void*)HF, up_b + l*2048, nullptr,
         4096, 2048, 512, 512, 512, 2048, 1, 0,0,0,0,0,0, 1, 1.f, 0);
    g128(stream, 3, HF, downwh + (long)l*1048576, x, down_b + l*512, nullptr,
         4096, 512, 2048, 2048, 2048, 512, 1, 0,0,0,0,0,0, 1, 1.f, 0);
  }

  ln_kernel<<<1024, 256, 0, stream>>>(x, nrmh, lnf_s, lnf_b);
  // logits (nontemporal C store)
  g128(stream, 4, nrmh, tembh, out, nullptr, nullptr,
       4096, 32000, 512, 512, 512, 32000, 1, 0,0,0,0,0,0, 1, 1.f, 0);
}

// Round 3
// 1388.278 us; speedup vs baseline: 1.7946x; 1.1777x over previous
//
#include <hip/hip_runtime.h>
#include <hip/hip_bf16.h>
#include <math.h>

typedef __attribute__((ext_vector_type(8))) short short8;
typedef __attribute__((ext_vector_type(4))) short short4v;
typedef __attribute__((ext_vector_type(8))) __bf16 bf16x8;
typedef __attribute__((ext_vector_type(4))) float f32x4;
typedef unsigned short ushort;

#define DEVI static __device__ __forceinline__

DEVI ushort f2bf(float f) {
  union { float f; unsigned u; } v; v.f = f;
  unsigned r = v.u + 0x7fffu + ((v.u >> 16) & 1u);
  return (ushort)(r >> 16);
}
DEVI float bf2f(ushort h) {
  union { unsigned u; float f; } v; v.u = (unsigned)h << 16; return v.f;
}
DEVI void gload16(const void* g, void* l) {
  __builtin_amdgcn_global_load_lds((const __attribute__((address_space(1))) void*)g,
                                   (__attribute__((address_space(3))) void*)l, 16, 0, 0);
}

// ---------------------------------------------------------------------------
// 128x128 bf16 MFMA GEMM (m97 structure): A [M,K] bf16, B [N,K] bf16 (B^T),
// BK=32, 4 waves, global_load_lds staging, bijective XCD swizzle.
// EPI: 0=f32 store, 1=bf16 store, 2=GELU->bf16, 3=f32 residual add, 4=f32 NT store
// ---------------------------------------------------------------------------
template<int EPI>
__global__ __launch_bounds__(256) void gemm128(
    const ushort* __restrict__ A, const ushort* __restrict__ B,
    void* __restrict__ Cv, const float* __restrict__ bias,
    const float* __restrict__ colmul,
    int K, int lda, int ldb, int ldc,
    long sA1, long sA2, long sB1, long sB2, long sC1, long sC2,
    int zdiv, float scale)
{
  __shared__ ushort As[4096];   // [128][32] linear
  __shared__ ushort Bs[4096];
  const int z = blockIdx.z; const int z1 = z / zdiv, z2 = z - z1 * zdiv;
  A += (long)z1 * sA1 + (long)z2 * sA2;
  B += (long)z1 * sB1 + (long)z2 * sB2;
  const long coff = (long)z1 * sC1 + (long)z2 * sC2;

  const int gx = gridDim.x;
  const int nwg = gx * gridDim.y;
  const int orig = blockIdx.y * gx + blockIdx.x;
  const int q = nwg >> 3, r = nwg & 7;
  const int xcd = orig & 7, sidx = orig >> 3;
  const int wg = (xcd < r ? xcd * (q + 1) : r * (q + 1) + (xcd - r) * q) + sidx;
  const int n0 = (wg % gx) * 128, m0 = (wg / gx) * 128;

  const int tid = threadIdx.x;
  const int arow = tid >> 2, acolb = (tid & 3) << 4;
  const int lane = tid & 63, wv = tid >> 6;
  const int wm = wv >> 1, wn = wv & 1;
  const int l16 = lane & 15, lq = lane >> 4;

  f32x4 acc[4][4];
#pragma unroll
  for (int i = 0; i < 4; i++)
#pragma unroll
    for (int j = 0; j < 4; j++) acc[i][j] = (f32x4){0.f, 0.f, 0.f, 0.f};

  const char* Ab = (const char*)(A + (long)(m0 + arow) * lda) + acolb;
  const char* Bb = (const char*)(B + (long)(n0 + arow) * ldb) + acolb;
  const long a64 = (long)64 * lda * 2, b64 = (long)64 * ldb * 2;
  char* la = (char*)As + tid * 16;
  char* lb = (char*)Bs + tid * 16;

  for (int k0 = 0; k0 < K; k0 += 32) {
    const char* ap = Ab + (long)k0 * 2;
    const char* bp = Bb + (long)k0 * 2;
    gload16(ap, la);
    gload16(ap + a64, la + 4096);
    gload16(bp, lb);
    gload16(bp + b64, lb + 4096);
    __syncthreads();
    bf16x8 af[4], bfr[4];
#pragma unroll
    for (int i = 0; i < 4; i++) {
      af[i]  = __builtin_bit_cast(bf16x8, *(const short8*)&As[(wm*64 + i*16 + l16)*32 + lq*8]);
      bfr[i] = __builtin_bit_cast(bf16x8, *(const short8*)&Bs[(wn*64 + i*16 + l16)*32 + lq*8]);
    }
#pragma unroll
    for (int i = 0; i < 4; i++)
#pragma unroll
      for (int j = 0; j < 4; j++)
        acc[i][j] = __builtin_amdgcn_mfma_f32_16x16x32_bf16(af[i], bfr[j], acc[i][j], 0, 0, 0);
    __syncthreads();
  }

  float* Cf = (float*)Cv;
  ushort* Ch = (ushort*)Cv;
#pragma unroll
  for (int i = 0; i < 4; i++) {
    const int row0 = m0 + wm*64 + i*16 + lq*4;
#pragma unroll
    for (int j = 0; j < 4; j++) {
      const int col = n0 + wn*64 + j*16 + l16;
      const float cb = bias ? bias[col] : 0.f;
      const float cm = colmul ? colmul[col] : 1.f;
#pragma unroll
      for (int t = 0; t < 4; t++) {
        float val = acc[i][j][t] * scale + cb;
        val *= cm;
        const long idx = coff + (long)(row0 + t) * ldc + col;
        if (EPI == 0)      Cf[idx] = val;
        else if (EPI == 1) Ch[idx] = f2bf(val);
        else if (EPI == 2) { val = 0.5f * val * (1.f + erff(val * 0.70710678118654752f)); Ch[idx] = f2bf(val); }
        else if (EPI == 3) Cf[idx] += val;
        else               __builtin_nontemporal_store(val, Cf + idx);
      }
    }
  }
}

// ---------------------------------------------------------------------------
// Fused causal flash attention. qk: [4096,1024] bf16 (cols 0-511 Q, 512-1023 K,
// heads of 64). v: [4096,512] bf16. o: [4096,512] bf16.
// Grid (8 pair, 32 bh), 256 threads. Pair p handles q-tiles {p, 15-p} (64 rows
// each) -> 17 kv-tiles of 64 per block, balanced. scale=0.125.
// ---------------------------------------------------------------------------
__global__ __launch_bounds__(256) void flash_kernel(
    const ushort* __restrict__ qk, const ushort* __restrict__ v,
    ushort* __restrict__ o)
{
  __shared__ ushort Ks[4096];   // [64 kv][64 d] XOR-swizzled
  __shared__ ushort VTs[4096];  // [64 d][64 kv] XOR-swizzled
  __shared__ ushort Ps[4096];   // [64 q][64 kv] XOR-swizzled (per-wave rows)
  const int p = blockIdx.x, bh = blockIdx.y;
  const int b = bh >> 3, h = bh & 7;
  const int tid = threadIdx.x, lane = tid & 63, w = tid >> 6;
  const int l16 = lane & 15, lq = lane >> 4;
  const long tokbase = (long)b * 1024;
  const ushort* Qbase = qk + tokbase * 1024 + h * 64;
  const char*   Kbase = (const char*)(qk + tokbase * 1024 + 512 + h * 64);
  const ushort* Vbase = v + tokbase * 512 + h * 64;

  const int krow = tid >> 3, kcb = (tid & 7) << 4;  // K staging: row, byte col
  const int vkv  = tid >> 2, vdb = (tid & 3) << 4;  // V staging: kv row, d block

#pragma unroll 1
  for (int half = 0; half < 2; half++) {
    const int qt = half ? (15 - p) : p;
    const int q0 = qt * 64;
    const int ntiles = qt + 1;

    const ushort* qrow = Qbase + (long)(q0 + w*16 + l16) * 1024;
    const bf16x8 qf0 = *(const bf16x8*)(qrow + lq*8);
    const bf16x8 qf1 = *(const bf16x8*)(qrow + 32 + lq*8);

    float m_[4] = {-1e30f, -1e30f, -1e30f, -1e30f};
    float l_[4] = {0.f, 0.f, 0.f, 0.f};
    f32x4 od[4];
#pragma unroll
    for (int dt = 0; dt < 4; dt++) od[dt] = (f32x4){0.f, 0.f, 0.f, 0.f};

#pragma unroll 1
    for (int t = 0; t < ntiles; t++) {
      const long t0 = (long)t * 64;
      // stage K tile (linear LDS dest, inverse-swizzled global source)
      {
        const int swz = kcb ^ ((krow & 7) << 4);
        gload16(Kbase + (t0 + krow) * 2048 + swz, (char*)Ks + tid * 16);
        gload16(Kbase + (t0 + 32 + krow) * 2048 + swz, (char*)Ks + 4096 + tid * 16);
      }
      // stage V transposed (reg-stage, swizzled scalar writes)
      {
        const ushort* vr = Vbase + (t0 + vkv) * 512 + vdb;
        short8 va = *(const short8*)vr;
        short8 vb = *(const short8*)(vr + 8);
#pragma unroll
        for (int j = 0; j < 8; j++) {
          int d1 = vdb + j, d2 = vdb + 8 + j;
          *(ushort*)((char*)VTs + d1*128 + ((vkv*2) ^ ((d1 & 7) << 4))) = (ushort)va[j];
          *(ushort*)((char*)VTs + d2*128 + ((vkv*2) ^ ((d2 & 7) << 4))) = (ushort)vb[j];
        }
      }
      __syncthreads();

      // S = Q @ K^T
      f32x4 sa[4];
#pragma unroll
      for (int n = 0; n < 4; n++) sa[n] = (f32x4){0.f, 0.f, 0.f, 0.f};
#pragma unroll
      for (int ks = 0; ks < 2; ks++) {
        const bf16x8 qf = ks ? qf1 : qf0;
#pragma unroll
        for (int n = 0; n < 4; n++) {
          const int row = n*16 + l16;
          bf16x8 kf = *(const bf16x8*)((const char*)Ks + row*128 + ((ks*64 + lq*16) ^ ((row & 7) << 4)));
          sa[n] = __builtin_amdgcn_mfma_f32_16x16x32_bf16(qf, kf, sa[n], 0, 0, 0);
        }
      }

      // scale + causal mask + online softmax
      const bool diag = (t == qt);
      float rowmax[4] = {-1e30f, -1e30f, -1e30f, -1e30f};
#pragma unroll
      for (int n = 0; n < 4; n++)
#pragma unroll
        for (int r = 0; r < 4; r++) {
          float sv = sa[n][r] * 0.125f;
          if (diag && (n*16 + l16 > w*16 + lq*4 + r)) sv = -1e30f;
          sa[n][r] = sv;
          rowmax[r] = fmaxf(rowmax[r], sv);
        }
#pragma unroll
      for (int r = 0; r < 4; r++)
#pragma unroll
        for (int off = 8; off; off >>= 1) rowmax[r] = fmaxf(rowmax[r], __shfl_xor(rowmax[r], off));

      float psum[4];
#pragma unroll
      for (int r = 0; r < 4; r++) {
        const float mn = fmaxf(m_[r], rowmax[r]);
        const float corr = __expf(m_[r] - mn);
        m_[r] = mn;
        l_[r] *= corr;
#pragma unroll
        for (int dt = 0; dt < 4; dt++) od[dt][r] *= corr;
        psum[r] = 0.f;
      }
#pragma unroll
      for (int n = 0; n < 4; n++)
#pragma unroll
        for (int r = 0; r < 4; r++) {
          const float pv = __expf(sa[n][r] - m_[r]);
          psum[r] += pv;
          const int prow = w*16 + lq*4 + r;
          *(ushort*)((char*)Ps + prow*128 + (((n*16 + l16)*2) ^ ((prow & 7) << 4))) = f2bf(pv);
        }
#pragma unroll
      for (int r = 0; r < 4; r++) {
#pragma unroll
        for (int off = 8; off; off >>= 1) psum[r] += __shfl_xor(psum[r], off);
        l_[r] += psum[r];
      }

      // O += P @ V  (P rows are wave-private: no barrier needed)
#pragma unroll
      for (int ks = 0; ks < 2; ks++) {
        const int prow = w*16 + l16;
        bf16x8 pf = *(const bf16x8*)((const char*)Ps + prow*128 + ((ks*64 + lq*16) ^ ((prow & 7) << 4)));
#pragma unroll
        for (int dt = 0; dt < 4; dt++) {
          const int vrow = dt*16 + l16;
          bf16x8 vf = *(const bf16x8*)((const char*)VTs + vrow*128 + ((ks*64 + lq*16) ^ ((vrow & 7) << 4)));
          od[dt] = __builtin_amdgcn_mfma_f32_16x16x32_bf16(pf, vf, od[dt], 0, 0, 0);
        }
      }
      __syncthreads();
    }

    // write O / l
#pragma unroll
    for (int r = 0; r < 4; r++) {
      const float inv = 1.f / l_[r];
      ushort* orow = o + (tokbase + q0 + w*16 + lq*4 + r) * 512 + h * 64 + l16;
#pragma unroll
      for (int dt = 0; dt < 4; dt++) orow[dt*16] = f2bf(od[dt][r] * inv);
    }
  }
}

// ---------------------------------------------------------------------------
// small kernels
// ---------------------------------------------------------------------------
__global__ __launch_bounds__(256) void cvt_bf16(const float* __restrict__ src, ushort* __restrict__ dst) {
  long i = ((long)blockIdx.x * 256 + threadIdx.x) * 8;
  float4 u = *(const float4*)(src + i), v = *(const float4*)(src + i + 4);
  short8 s;
  s[0]=(short)f2bf(u.x); s[1]=(short)f2bf(u.y); s[2]=(short)f2bf(u.z); s[3]=(short)f2bf(u.w);
  s[4]=(short)f2bf(v.x); s[5]=(short)f2bf(v.y); s[6]=(short)f2bf(v.z); s[7]=(short)f2bf(v.w);
  *(short8*)(dst + i) = s;
}

__global__ __launch_bounds__(256) void mkqkb_kernel(const float* __restrict__ qb,
    const float* __restrict__ kb, float* __restrict__ qkb) {
  int i = blockIdx.x * 256 + threadIdx.x;     // 4096
  int l = i >> 10, c = i & 1023;
  qkb[i] = c < 512 ? qb[l*512 + c] : kb[l*512 + c - 512];
}

// basis_A [32][512][128] f32 -> basisAT [32][128][512] bf16
__global__ __launch_bounds__(256) void transpose_basisA(
    const float* __restrict__ src, ushort* __restrict__ dst)
{
  __shared__ ushort tile[64][132];
  const int n = blockIdx.x;
  const int d0 = blockIdx.y * 64;
  const int tid = threadIdx.x;
#pragma unroll
  for (int it = 0; it < 8; it++) {
    int d = it * 8 + (tid >> 5);
    int rr = (tid & 31) * 4;
    float4 v = *(const float4*)(src + ((long)n * 512 + d0 + d) * 128 + rr);
    tile[d][rr + 0] = f2bf(v.x);
    tile[d][rr + 1] = f2bf(v.y);
    tile[d][rr + 2] = f2bf(v.z);
    tile[d][rr + 3] = f2bf(v.w);
  }
  __syncthreads();
#pragma unroll
  for (int it = 0; it < 4; it++) {
    int rr = it * 32 + (tid >> 3);
    int dof = (tid & 7) * 8;
    short8 s;
#pragma unroll
    for (int j = 0; j < 8; j++) s[j] = (short)tile[dof + j][rr];
    *(short8*)(dst + ((long)n * 128 + rr) * 512 + d0 + dof) = s;
  }
}

__global__ __launch_bounds__(256) void embed_kernel(
    const int* __restrict__ ids, const float* __restrict__ tok,
    const float* __restrict__ pos, float* __restrict__ x)
{
  int i = blockIdx.x * 256 + threadIdx.x;
  int t = i >> 7, c = (i & 127) * 4;
  int sp = t & 1023;
  int id = ids[t];
  float4 a = *(const float4*)(tok + (long)id * 512 + c);
  float4 b = *(const float4*)(pos + (long)sp * 512 + c);
  float4 rr; rr.x=a.x+b.x; rr.y=a.y+b.y; rr.z=a.z+b.z; rr.w=a.w+b.w;
  *(float4*)(x + (long)t * 512 + c) = rr;
}

__global__ __launch_bounds__(256) void ln_kernel(
    const float* __restrict__ in, ushort* __restrict__ outh,
    const float* __restrict__ gam, const float* __restrict__ bet)
{
  int row = blockIdx.x * 4 + (threadIdx.x >> 6);
  int lane = threadIdx.x & 63;
  const float* p = in + (long)row * 512;
  float4 v0 = *(const float4*)(p + lane * 4);
  float4 v1 = *(const float4*)(p + 256 + lane * 4);
  float s = v0.x+v0.y+v0.z+v0.w + v1.x+v1.y+v1.z+v1.w;
#pragma unroll
  for (int o = 32; o; o >>= 1) s += __shfl_xor(s, o);
  float mean = s * (1.f/512.f);
  float d0=v0.x-mean, d1=v0.y-mean, d2=v0.z-mean, d3=v0.w-mean;
  float e0=v1.x-mean, e1=v1.y-mean, e2=v1.z-mean, e3=v1.w-mean;
  float qv = d0*d0+d1*d1+d2*d2+d3*d3 + e0*e0+e1*e1+e2*e2+e3*e3;
#pragma unroll
  for (int o = 32; o; o >>= 1) qv += __shfl_xor(qv, o);
  float inv = rsqrtf(qv * (1.f/512.f) + 1e-5f);
  float4 g0 = *(const float4*)(gam + lane*4);
  float4 g1 = *(const float4*)(gam + 256 + lane*4);
  float4 b0 = *(const float4*)(bet + lane*4);
  float4 b1 = *(const float4*)(bet + 256 + lane*4);
  short4v o0, o1;
  o0[0]=(short)f2bf(d0*inv*g0.x + b0.x); o0[1]=(short)f2bf(d1*inv*g0.y + b0.y);
  o0[2]=(short)f2bf(d2*inv*g0.z + b0.z); o0[3]=(short)f2bf(d3*inv*g0.w + b0.w);
  o1[0]=(short)f2bf(e0*inv*g1.x + b1.x); o1[1]=(short)f2bf(e1*inv*g1.y + b1.y);
  o1[2]=(short)f2bf(e2*inv*g1.z + b1.z); o1[3]=(short)f2bf(e3*inv*g1.w + b1.w);
  *(short4v*)(outh + (long)row*512 + lane*4) = o0;
  *(short4v*)(outh + (long)row*512 + 256 + lane*4) = o1;
}

__global__ __launch_bounds__(64) void precompute_kernel(
    const float* __restrict__ recipe, const float* __restrict__ basis_emb,
    const float* __restrict__ ctx_pat, float* __restrict__ rec_sm,
    ushort* __restrict__ emb_sem, float* __restrict__ gate)
{
  int ln = blockIdx.x;
  int lane = threadIdx.x;
  const float* r = recipe + (long)ln * 32;
  float rv[32];
  float m = -1e30f;
#pragma unroll
  for (int j = 0; j < 32; j++) { rv[j] = r[j]; m = fmaxf(m, rv[j]); }
  float sum = 0.f;
#pragma unroll
  for (int j = 0; j < 32; j++) { rv[j] = expf(rv[j] - m); sum += rv[j]; }
  float inv = 1.f / sum;
#pragma unroll
  for (int j = 0; j < 32; j++) rv[j] *= inv;
  if (lane < 32) rec_sm[(long)ln * 32 + lane] = rv[lane];
#pragma unroll
  for (int cc = 0; cc < 8; cc++) {
    int c = lane + cc * 64;
    float acc = 0.f;
#pragma unroll
    for (int j = 0; j < 32; j++) acc += rv[j] * basis_emb[j * 512 + c];
    emb_sem[(long)ln * 512 + c] = f2bf(acc);
  }
  if (lane == 0) {
    float sh = 0.f;
#pragma unroll
    for (int h = 0; h < 8; h++) sh += ctx_pat[(long)ln * 8 + h];
    gate[ln] = 1.f / (1.f + expf(-sh * (1.f/1024.f)));
  }
}

__global__ __launch_bounds__(256) void topk_kernel(
    const float* __restrict__ fin, const float* __restrict__ rec_sm_l,
    float* __restrict__ tr)
{
  int t = blockIdx.x * 4 + (threadIdx.x >> 6);
  int lane = threadIdx.x & 63;
  const float* f = fin + (long)t * 256;
  float v0 = f[lane], v1 = f[lane+64], v2 = f[lane+128], v3 = f[lane+192];
  int i0 = lane, i1 = lane+64, i2 = lane+128, i3 = lane+192;
  float topv[8]; int topi[8];
#pragma unroll
  for (int it = 0; it < 8; it++) {
    float bm = v0; int bi = i0;
    if (v1 > bm || (v1 == bm && i1 < bi)) { bm = v1; bi = i1; }
    if (v2 > bm || (v2 == bm && i2 < bi)) { bm = v2; bi = i2; }
    if (v3 > bm || (v3 == bm && i3 < bi)) { bm = v3; bi = i3; }
#pragma unroll
    for (int o = 32; o; o >>= 1) {
      float om = __shfl_xor(bm, o);
      int oi = __shfl_xor(bi, o);
      if (om > bm || (om == bm && oi < bi)) { bm = om; bi = oi; }
    }
    topv[it] = bm; topi[it] = bi;
    if (i0 == bi) v0 = -1e30f;
    if (i1 == bi) v1 = -1e30f;
    if (i2 == bi) v2 = -1e30f;
    if (i3 == bi) v3 = -1e30f;
  }
  float w[8], wsum = 0.f;
#pragma unroll
  for (int k = 0; k < 8; k++) { w[k] = expf(topv[k] - topv[0]); wsum += w[k]; }
  float inv = 1.f / wsum;
  if (lane < 32) {
    float acc = 0.f;
#pragma unroll
    for (int k = 0; k < 8; k++)
      acc += (w[k] * inv) * rec_sm_l[(long)topi[k] * 32 + lane];
    tr[(long)t * 32 + lane] = acc;
  }
}

__global__ __launch_bounds__(256) void vsem_kernel(
    const ushort* __restrict__ XA, const float* __restrict__ tr,
    ushort* __restrict__ out)
{
  int t = blockIdx.x * 4 + (threadIdx.x >> 6);
  int lane = threadIdx.x & 63;
  const ushort* xa = XA + (long)t * 4096;
  const float* tt = tr + (long)t * 32;
  float a0 = 0.f, a1 = 0.f;
#pragma unroll
  for (int n = 0; n < 32; n++) {
    float w = tt[n];
    a0 += w * bf2f(xa[n*128 + lane]);
    a1 += w * bf2f(xa[n*128 + 64 + lane]);
  }
  out[(long)t * 128 + lane] = f2bf(a0);
  out[(long)t * 128 + 64 + lane] = f2bf(a1);
}

// ---------------------------------------------------------------------------
// host
// ---------------------------------------------------------------------------
static inline void g128(hipStream_t st, int epi,
                        const ushort* A, const ushort* B, void* C,
                        const float* bias, const float* colmul,
                        int M, int N, int K, int lda, int ldb, int ldc, int nb,
                        long sA1, long sA2, long sB1, long sB2, long sC1, long sC2,
                        int zdiv, float scale)
{
  dim3 g(N/128, M/128, nb), b(256);
#define GK(E) gemm128<E><<<g,b,0,st>>>(A,B,C,bias,colmul,K,lda,ldb,ldc,sA1,sA2,sB1,sB2,sC1,sC2,zdiv,scale)
  switch (epi) {
    case 0: GK(0); break; case 1: GK(1); break; case 2: GK(2); break;
    case 3: GK(3); break; default: GK(4); break;
  }
#undef GK
}

extern "C" void kernel_launch(void* const* d_in, const int* in_sizes, int n_in,
                              void* d_out, int out_size, void* d_ws, size_t ws_size,
                              hipStream_t stream) {
  (void)in_sizes; (void)n_in; (void)out_size; (void)ws_size;
  const int*   ids       = (const int*)  d_in[0];
  const float* token_emb = (const float*)d_in[1];
  const float* pos_emb   = (const float*)d_in[2];
  const float* basis_A   = (const float*)d_in[3];
  const float* basis_emb = (const float*)d_in[4];
  const float* q_w  = (const float*)d_in[5];
  const float* q_b  = (const float*)d_in[6];
  const float* k_w  = (const float*)d_in[7];
  const float* k_b  = (const float*)d_in[8];
  const float* ao_w = (const float*)d_in[9];
  const float* ao_b = (const float*)d_in[10];
  const float* recipe  = (const float*)d_in[11];
  const float* ctx_pat = (const float*)d_in[12];
  const float* vout_w  = (const float*)d_in[13];
  const float* vout_b  = (const float*)d_in[14];
  const float* up_w    = (const float*)d_in[15];
  const float* up_b    = (const float*)d_in[16];
  const float* down_w  = (const float*)d_in[17];
  const float* down_b  = (const float*)d_in[18];
  const float* ln1_s = (const float*)d_in[19];
  const float* ln1_b = (const float*)d_in[20];
  const float* ln2_s = (const float*)d_in[21];
  const float* ln2_b = (const float*)d_in[22];
  const float* lnf_s = (const float*)d_in[23];
  const float* lnf_b = (const float*)d_in[24];
  float* out = (float*)d_out;

  // ws layout
  float* ws    = (float*)d_ws;
  float* x     = ws;                 // [4096,512] f32
  float* finb  = x + 2097152;        // [4096,256] f32
  float* trb   = finb + 1048576;     // [4096,32] f32
  float* recsm = trb + 131072;       // [4,256,32] f32
  float* gate  = recsm + 32768;      // [4,256] f32
  float* qkb   = gate + 1024;        // [4,1024] f32
  ushort* u = (ushort*)(qkb + 4096);
  ushort* nrmh    = u; u += 2097152;   // [4096,512]
  ushort* qkh     = u; u += 4194304;   // [4096,1024]  Q|K
  ushort* vvh     = u; u += 2097152;   // [4096,512]
  ushort* aoh     = u; u += 2097152;   // [4096,512]
  ushort* vsemh   = u; u += 524288;    // [4096,128]
  ushort* embsem  = u; u += 524288;    // [4,256,512]
  ushort* qkwh    = u; u += 2097152;   // [4,1024,512]
  ushort* aowh    = u; u += 1048576;   // [4,512,512]
  ushort* voutwh  = u; u += 262144;    // [4,512,128]
  ushort* upwh    = u; u += 4194304;   // [4,2048,512]
  ushort* downwh  = u; u += 4194304;   // [4,512,2048]
  ushort* tembh   = u; u += 16384000;  // [32000,512]
  ushort* basisAT = u; u += 2097152;   // [32][128][512]

  // big transients in d_out (disjoint lifetimes, overwritten by logits)
  ushort* XAb = (ushort*)out;          // [4096,32,128] bf16
  ushort* HF  = (ushort*)out;          // [4096,2048] bf16

  // one-time conversions
  for (int l = 0; l < 4; l++) {
    cvt_bf16<<<128, 256, 0, stream>>>(q_w + (long)l*262144, qkwh + (long)l*524288);
    cvt_bf16<<<128, 256, 0, stream>>>(k_w + (long)l*262144, qkwh + (long)l*524288 + 262144);
  }
  mkqkb_kernel<<<16, 256, 0, stream>>>(q_b, k_b, qkb);
  cvt_bf16<<<512, 256, 0, stream>>>(ao_w, aowh);
  cvt_bf16<<<128, 256, 0, stream>>>(vout_w, voutwh);
  cvt_bf16<<<2048, 256, 0, stream>>>(up_w, upwh);
  cvt_bf16<<<2048, 256, 0, stream>>>(down_w, downwh);
  cvt_bf16<<<8000, 256, 0, stream>>>(token_emb, tembh);
  transpose_basisA<<<dim3(32, 8), 256, 0, stream>>>(basis_A, basisAT);
  embed_kernel<<<2048, 256, 0, stream>>>(ids, token_emb, pos_emb, x);
  precompute_kernel<<<1024, 64, 0, stream>>>(recipe, basis_emb, ctx_pat, recsm, embsem, gate);

  for (int l = 0; l < 4; l++) {
    ln_kernel<<<1024, 256, 0, stream>>>(x, nrmh, ln1_s + l*512, ln1_b + l*512);
    // fin = (nrm @ emb_sem^T) * gate
    g128(stream, 0, nrmh, embsem + (long)l*131072, finb, nullptr, gate + l*256,
         4096, 256, 512, 512, 512, 256, 1, 0,0,0,0,0,0, 1, 1.f);
    topk_kernel<<<1024, 256, 0, stream>>>(finb, recsm + (long)l*8192, trb);
    // xA (batched over n)
    g128(stream, 1, nrmh, basisAT, (void*)XAb, nullptr, nullptr,
         4096, 128, 512, 512, 512, 4096, 32, 0,0, 0,65536, 0,128, 32, 1.f);
    vsem_kernel<<<1024, 256, 0, stream>>>(XAb, trb, vsemh);
    // Vv = v_sem @ vout_w^T + vout_b
    g128(stream, 1, vsemh, voutwh + (long)l*65536, vvh, vout_b + l*512, nullptr,
         4096, 512, 128, 128, 128, 512, 1, 0,0,0,0,0,0, 1, 1.f);
    // Q|K merged projection -> [4096,1024]
    g128(stream, 1, nrmh, qkwh + (long)l*524288, qkh, qkb + l*1024, nullptr,
         4096, 1024, 512, 512, 512, 1024, 1, 0,0,0,0,0,0, 1, 1.f);
    // fused flash attention -> aoh
    flash_kernel<<<dim3(8, 32), 256, 0, stream>>>(qkh, vvh, aoh);
    // x += ao @ ao_w^T + ao_b
    g128(stream, 3, aoh, aowh + (long)l*262144, x, ao_b + l*512, nullptr,
         4096, 512, 512, 512, 512, 512, 1, 0,0,0,0,0,0, 1, 1.f);
    // FFN
    ln_kernel<<<1024, 256, 0, stream>>>(x, nrmh, ln2_s + l*512, ln2_b + l*512);
    g128(stream, 2, nrmh, upwh + (long)l*1048576, (void*)HF, up_b + l*2048, nullptr,
         4096, 2048, 512, 512, 512, 2048, 1, 0,0,0,0,0,0, 1, 1.f);
    g128(stream, 3, HF, downwh + (long)l*1048576, x, down_b + l*512, nullptr,
         4096, 512, 2048, 2048, 2048, 512, 1, 0,0,0,0,0,0, 1, 1.f);
  }

  ln_kernel<<<1024, 256, 0, stream>>>(x, nrmh, lnf_s, lnf_b);
  // logits (nontemporal C store)
  g128(stream, 4, nrmh, tembh, out, nullptr, nullptr,
       4096, 32000, 512, 512, 512, 32000, 1, 0,0,0,0,0,0, 1, 1.f);
}

// Round 4
// 1132.777 us; speedup vs baseline: 2.1994x; 1.2256x over previous
//
#include <hip/hip_runtime.h>
#include <hip/hip_bf16.h>
#include <math.h>

typedef __attribute__((ext_vector_type(8))) short short8;
typedef __attribute__((ext_vector_type(4))) short short4v;
typedef __attribute__((ext_vector_type(8))) __bf16 bf16x8;
typedef __attribute__((ext_vector_type(4))) float f32x4;
typedef unsigned short ushort;

#define DEVI static __device__ __forceinline__

DEVI ushort f2bf(float f) {
  union { float f; unsigned u; } v; v.f = f;
  unsigned r = v.u + 0x7fffu + ((v.u >> 16) & 1u);
  return (ushort)(r >> 16);
}
DEVI float bf2f(ushort h) {
  union { unsigned u; float f; } v; v.u = (unsigned)h << 16; return v.f;
}
DEVI void gload16(const void* g, void* l) {
  __builtin_amdgcn_global_load_lds((const __attribute__((address_space(1))) void*)g,
                                   (__attribute__((address_space(3))) void*)l, 16, 0, 0);
}

// ---------------------------------------------------------------------------
// BMx128 bf16 MFMA GEMM (m97 structure): A [M,K] bf16, B [N,K] bf16 (B^T),
// BK=32, 4 waves, global_load_lds, bijective XCD swizzle. BM in {64,128}.
// EPI: 1=bf16 store, 2=GELU->bf16, 3=f32 residual add, 4=f32 NT store
// ---------------------------------------------------------------------------
template<int BM, int EPI>
__global__ __launch_bounds__(256) void gemmT(
    const ushort* __restrict__ A, const ushort* __restrict__ B,
    void* __restrict__ Cv, const float* __restrict__ bias,
    int K, int lda, int ldb, int ldc, float scale)
{
  constexpr int MF = BM / 32;   // m-fragments per wave
  constexpr int MH = BM / 2;    // rows per wave-half
  __shared__ ushort As[BM * 32];
  __shared__ ushort Bs[4096];

  const int gx = gridDim.x;
  const int nwg = gx * gridDim.y;
  const int orig = blockIdx.y * gx + blockIdx.x;
  const int q = nwg >> 3, r = nwg & 7;
  const int xcd = orig & 7, sidx = orig >> 3;
  const int wg = (xcd < r ? xcd * (q + 1) : r * (q + 1) + (xcd - r) * q) + sidx;
  const int n0 = (wg % gx) * 128, m0 = (wg / gx) * BM;

  const int tid = threadIdx.x;
  const int arow = tid >> 2, acolb = (tid & 3) << 4;
  const int lane = tid & 63, wv = tid >> 6;
  const int wm = wv >> 1, wn = wv & 1;
  const int l16 = lane & 15, lq = lane >> 4;

  f32x4 acc[MF][4];
#pragma unroll
  for (int i = 0; i < MF; i++)
#pragma unroll
    for (int j = 0; j < 4; j++) acc[i][j] = (f32x4){0.f, 0.f, 0.f, 0.f};

  const char* Ab = (const char*)(A + (long)(m0 + arow) * lda) + acolb;
  const char* Bb = (const char*)(B + (long)(n0 + arow) * ldb) + acolb;
  const long a64 = (long)64 * lda * 2, b64 = (long)64 * ldb * 2;
  char* la = (char*)As + tid * 16;
  char* lb = (char*)Bs + tid * 16;

  for (int k0 = 0; k0 < K; k0 += 32) {
    const char* ap = Ab + (long)k0 * 2;
    const char* bp = Bb + (long)k0 * 2;
#pragma unroll
    for (int s = 0; s < BM / 64; s++) gload16(ap + s * a64, la + s * 4096);
    gload16(bp, lb);
    gload16(bp + b64, lb + 4096);
    __syncthreads();
    bf16x8 af[MF], bfr[4];
#pragma unroll
    for (int i = 0; i < MF; i++)
      af[i] = __builtin_bit_cast(bf16x8, *(const short8*)&As[(wm*MH + i*16 + l16)*32 + lq*8]);
#pragma unroll
    for (int j = 0; j < 4; j++)
      bfr[j] = __builtin_bit_cast(bf16x8, *(const short8*)&Bs[(wn*64 + j*16 + l16)*32 + lq*8]);
#pragma unroll
    for (int i = 0; i < MF; i++)
#pragma unroll
      for (int j = 0; j < 4; j++)
        acc[i][j] = __builtin_amdgcn_mfma_f32_16x16x32_bf16(af[i], bfr[j], acc[i][j], 0, 0, 0);
    __syncthreads();
  }

  float* Cf = (float*)Cv;
  ushort* Ch = (ushort*)Cv;
#pragma unroll
  for (int i = 0; i < MF; i++) {
    const int row0 = m0 + wm*MH + i*16 + lq*4;
#pragma unroll
    for (int j = 0; j < 4; j++) {
      const int col = n0 + wn*64 + j*16 + l16;
      const float cb = bias ? bias[col] : 0.f;
#pragma unroll
      for (int t = 0; t < 4; t++) {
        float val = acc[i][j][t] * scale + cb;
        const long idx = (long)(row0 + t) * ldc + col;
        if (EPI == 1)      Ch[idx] = f2bf(val);
        else if (EPI == 2) { val = 0.5f * val * (1.f + erff(val * 0.70710678118654752f)); Ch[idx] = f2bf(val); }
        else if (EPI == 3) Cf[idx] += val;
        else               __builtin_nontemporal_store(val, Cf + idx);
      }
    }
  }
}

// ---------------------------------------------------------------------------
// Mega GEMM: A=nrm [4096,512], B=Bcat[l] [5376,512] (rows: 256 emb_sem |
// 512 q_w | 512 k_w | 4096 basisAT). Grid (42,32). Epilogue routes by n-block:
// cols 0-255 -> finb f32 * gate; 256-1279 -> qkh bf16 + qkbias; rest -> XAb bf16.
// ---------------------------------------------------------------------------
__global__ __launch_bounds__(256) void megag1(
    const ushort* __restrict__ A, const ushort* __restrict__ B,
    float* __restrict__ finb, ushort* __restrict__ qkh, ushort* __restrict__ XAb,
    const float* __restrict__ gate, const float* __restrict__ qkbias)
{
  __shared__ ushort As[4096];
  __shared__ ushort Bs[4096];
  const int gx = gridDim.x;
  const int nwg = gx * gridDim.y;
  const int orig = blockIdx.y * gx + blockIdx.x;
  const int q = nwg >> 3, r = nwg & 7;
  const int xcd = orig & 7, sidx = orig >> 3;
  const int wg = (xcd < r ? xcd * (q + 1) : r * (q + 1) + (xcd - r) * q) + sidx;
  const int n0 = (wg % gx) * 128, m0 = (wg / gx) * 128;

  const int tid = threadIdx.x;
  const int arow = tid >> 2, acolb = (tid & 3) << 4;
  const int lane = tid & 63, wv = tid >> 6;
  const int wm = wv >> 1, wn = wv & 1;
  const int l16 = lane & 15, lq = lane >> 4;

  f32x4 acc[4][4];
#pragma unroll
  for (int i = 0; i < 4; i++)
#pragma unroll
    for (int j = 0; j < 4; j++) acc[i][j] = (f32x4){0.f, 0.f, 0.f, 0.f};

  const char* Ab = (const char*)(A + (long)(m0 + arow) * 512) + acolb;
  const char* Bb = (const char*)(B + (long)(n0 + arow) * 512) + acolb;
  const long a64 = (long)64 * 512 * 2;
  char* la = (char*)As + tid * 16;
  char* lb = (char*)Bs + tid * 16;

  for (int k0 = 0; k0 < 512; k0 += 32) {
    const char* ap = Ab + (long)k0 * 2;
    const char* bp = Bb + (long)k0 * 2;
    gload16(ap, la);
    gload16(ap + a64, la + 4096);
    gload16(bp, lb);
    gload16(bp + a64, lb + 4096);
    __syncthreads();
    bf16x8 af[4], bfr[4];
#pragma unroll
    for (int i = 0; i < 4; i++) {
      af[i]  = __builtin_bit_cast(bf16x8, *(const short8*)&As[(wm*64 + i*16 + l16)*32 + lq*8]);
      bfr[i] = __builtin_bit_cast(bf16x8, *(const short8*)&Bs[(wn*64 + i*16 + l16)*32 + lq*8]);
    }
#pragma unroll
    for (int i = 0; i < 4; i++)
#pragma unroll
      for (int j = 0; j < 4; j++)
        acc[i][j] = __builtin_amdgcn_mfma_f32_16x16x32_bf16(af[i], bfr[j], acc[i][j], 0, 0, 0);
    __syncthreads();
  }

#pragma unroll
  for (int i = 0; i < 4; i++) {
    const int row0 = m0 + wm*64 + i*16 + lq*4;
#pragma unroll
    for (int j = 0; j < 4; j++) {
      const int col = n0 + wn*64 + j*16 + l16;
      if (col < 256) {
        const float g = gate[col];
#pragma unroll
        for (int t = 0; t < 4; t++) finb[(long)(row0 + t) * 256 + col] = acc[i][j][t] * g;
      } else if (col < 1280) {
        const int c = col - 256;
        const float bb = qkbias[c];
#pragma unroll
        for (int t = 0; t < 4; t++) qkh[(long)(row0 + t) * 1024 + c] = f2bf(acc[i][j][t] + bb);
      } else {
        const int c = col - 1280;
#pragma unroll
        for (int t = 0; t < 4; t++) XAb[(long)(row0 + t) * 4096 + c] = f2bf(acc[i][j][t]);
      }
    }
  }
}

// ---------------------------------------------------------------------------
// Fused causal flash attention (unchanged from round 3).
// ---------------------------------------------------------------------------
__global__ __launch_bounds__(256) void flash_kernel(
    const ushort* __restrict__ qk, const ushort* __restrict__ v,
    ushort* __restrict__ o)
{
  __shared__ ushort Ks[4096];
  __shared__ ushort VTs[4096];
  __shared__ ushort Ps[4096];
  const int p = blockIdx.x, bh = blockIdx.y;
  const int b = bh >> 3, h = bh & 7;
  const int tid = threadIdx.x, lane = tid & 63, w = tid >> 6;
  const int l16 = lane & 15, lq = lane >> 4;
  const long tokbase = (long)b * 1024;
  const ushort* Qbase = qk + tokbase * 1024 + h * 64;
  const char*   Kbase = (const char*)(qk + tokbase * 1024 + 512 + h * 64);
  const ushort* Vbase = v + tokbase * 512 + h * 64;

  const int krow = tid >> 3, kcb = (tid & 7) << 4;
  const int vkv  = tid >> 2, vdb = (tid & 3) << 4;

#pragma unroll 1
  for (int half = 0; half < 2; half++) {
    const int qt = half ? (15 - p) : p;
    const int q0 = qt * 64;
    const int ntiles = qt + 1;

    const ushort* qrow = Qbase + (long)(q0 + w*16 + l16) * 1024;
    const bf16x8 qf0 = *(const bf16x8*)(qrow + lq*8);
    const bf16x8 qf1 = *(const bf16x8*)(qrow + 32 + lq*8);

    float m_[4] = {-1e30f, -1e30f, -1e30f, -1e30f};
    float l_[4] = {0.f, 0.f, 0.f, 0.f};
    f32x4 od[4];
#pragma unroll
    for (int dt = 0; dt < 4; dt++) od[dt] = (f32x4){0.f, 0.f, 0.f, 0.f};

#pragma unroll 1
    for (int t = 0; t < ntiles; t++) {
      const long t0 = (long)t * 64;
      {
        const int swz = kcb ^ ((krow & 7) << 4);
        gload16(Kbase + (t0 + krow) * 2048 + swz, (char*)Ks + tid * 16);
        gload16(Kbase + (t0 + 32 + krow) * 2048 + swz, (char*)Ks + 4096 + tid * 16);
      }
      {
        const ushort* vr = Vbase + (t0 + vkv) * 512 + vdb;
        short8 va = *(const short8*)vr;
        short8 vb = *(const short8*)(vr + 8);
#pragma unroll
        for (int j = 0; j < 8; j++) {
          int d1 = vdb + j, d2 = vdb + 8 + j;
          *(ushort*)((char*)VTs + d1*128 + ((vkv*2) ^ ((d1 & 7) << 4))) = (ushort)va[j];
          *(ushort*)((char*)VTs + d2*128 + ((vkv*2) ^ ((d2 & 7) << 4))) = (ushort)vb[j];
        }
      }
      __syncthreads();

      f32x4 sa[4];
#pragma unroll
      for (int n = 0; n < 4; n++) sa[n] = (f32x4){0.f, 0.f, 0.f, 0.f};
#pragma unroll
      for (int ks = 0; ks < 2; ks++) {
        const bf16x8 qf = ks ? qf1 : qf0;
#pragma unroll
        for (int n = 0; n < 4; n++) {
          const int row = n*16 + l16;
          bf16x8 kf = *(const bf16x8*)((const char*)Ks + row*128 + ((ks*64 + lq*16) ^ ((row & 7) << 4)));
          sa[n] = __builtin_amdgcn_mfma_f32_16x16x32_bf16(qf, kf, sa[n], 0, 0, 0);
        }
      }

      const bool diag = (t == qt);
      float rowmax[4] = {-1e30f, -1e30f, -1e30f, -1e30f};
#pragma unroll
      for (int n = 0; n < 4; n++)
#pragma unroll
        for (int r = 0; r < 4; r++) {
          float sv = sa[n][r] * 0.125f;
          if (diag && (n*16 + l16 > w*16 + lq*4 + r)) sv = -1e30f;
          sa[n][r] = sv;
          rowmax[r] = fmaxf(rowmax[r], sv);
        }
#pragma unroll
      for (int r = 0; r < 4; r++)
#pragma unroll
        for (int off = 8; off; off >>= 1) rowmax[r] = fmaxf(rowmax[r], __shfl_xor(rowmax[r], off));

      float psum[4];
#pragma unroll
      for (int r = 0; r < 4; r++) {
        const float mn = fmaxf(m_[r], rowmax[r]);
        const float corr = __expf(m_[r] - mn);
        m_[r] = mn;
        l_[r] *= corr;
#pragma unroll
        for (int dt = 0; dt < 4; dt++) od[dt][r] *= corr;
        psum[r] = 0.f;
      }
#pragma unroll
      for (int n = 0; n < 4; n++)
#pragma unroll
        for (int r = 0; r < 4; r++) {
          const float pv = __expf(sa[n][r] - m_[r]);
          psum[r] += pv;
          const int prow = w*16 + lq*4 + r;
          *(ushort*)((char*)Ps + prow*128 + (((n*16 + l16)*2) ^ ((prow & 7) << 4))) = f2bf(pv);
        }
#pragma unroll
      for (int r = 0; r < 4; r++) {
#pragma unroll
        for (int off = 8; off; off >>= 1) psum[r] += __shfl_xor(psum[r], off);
        l_[r] += psum[r];
      }

#pragma unroll
      for (int ks = 0; ks < 2; ks++) {
        const int prow = w*16 + l16;
        bf16x8 pf = *(const bf16x8*)((const char*)Ps + prow*128 + ((ks*64 + lq*16) ^ ((prow & 7) << 4)));
#pragma unroll
        for (int dt = 0; dt < 4; dt++) {
          const int vrow = dt*16 + l16;
          bf16x8 vf = *(const bf16x8*)((const char*)VTs + vrow*128 + ((ks*64 + lq*16) ^ ((vrow & 7) << 4)));
          od[dt] = __builtin_amdgcn_mfma_f32_16x16x32_bf16(pf, vf, od[dt], 0, 0, 0);
        }
      }
      __syncthreads();
    }

#pragma unroll
    for (int r = 0; r < 4; r++) {
      const float inv = 1.f / l_[r];
      ushort* orow = o + (tokbase + q0 + w*16 + lq*4 + r) * 512 + h * 64 + l16;
#pragma unroll
      for (int dt = 0; dt < 4; dt++) orow[dt*16] = f2bf(od[dt][r] * inv);
    }
  }
}

// ---------------------------------------------------------------------------
// small kernels
// ---------------------------------------------------------------------------
__global__ __launch_bounds__(256) void cvt_bf16(const float* __restrict__ src, ushort* __restrict__ dst) {
  long i = ((long)blockIdx.x * 256 + threadIdx.x) * 8;
  float4 u = *(const float4*)(src + i), v = *(const float4*)(src + i + 4);
  short8 s;
  s[0]=(short)f2bf(u.x); s[1]=(short)f2bf(u.y); s[2]=(short)f2bf(u.z); s[3]=(short)f2bf(u.w);
  s[4]=(short)f2bf(v.x); s[5]=(short)f2bf(v.y); s[6]=(short)f2bf(v.z); s[7]=(short)f2bf(v.w);
  *(short8*)(dst + i) = s;
}

// q_w/k_w (all 4 layers) -> Bcat rows 256..1279 per layer
__global__ __launch_bounds__(256) void qkcvt_kernel(
    const float* __restrict__ q_w, const float* __restrict__ k_w, ushort* __restrict__ Bcat)
{
  long e = ((long)blockIdx.x * 256 + threadIdx.x) * 8;   // < 2,097,152
  int l = (int)(e >> 19);
  long rem = e & 524287;
  bool isk = rem >= 262144;
  long so = rem & 262143;
  const float* src = (isk ? k_w : q_w) + (long)l * 262144 + so;
  ushort* dst = Bcat + (long)l * 2752512 + 131072 + (isk ? 262144 : 0) + so;
  float4 u = *(const float4*)src, v = *(const float4*)(src + 4);
  short8 s;
  s[0]=(short)f2bf(u.x); s[1]=(short)f2bf(u.y); s[2]=(short)f2bf(u.z); s[3]=(short)f2bf(u.w);
  s[4]=(short)f2bf(v.x); s[5]=(short)f2bf(v.y); s[6]=(short)f2bf(v.z); s[7]=(short)f2bf(v.w);
  *(short8*)dst = s;
}

__global__ __launch_bounds__(256) void mkqkb_kernel(const float* __restrict__ qb,
    const float* __restrict__ kb, float* __restrict__ qkb) {
  int i = blockIdx.x * 256 + threadIdx.x;
  int l = i >> 10, c = i & 1023;
  qkb[i] = c < 512 ? qb[l*512 + c] : kb[l*512 + c - 512];
}

// basis_A [32][512][128] f32 -> Bcat[l] rows 1280.. as [32][128][512] bf16, per layer z
__global__ __launch_bounds__(256) void transpose_basisA(
    const float* __restrict__ src, ushort* __restrict__ Bcat)
{
  __shared__ ushort tile[64][132];
  const int n = blockIdx.x;
  const int d0 = blockIdx.y * 64;
  const int l = blockIdx.z;
  ushort* dst = Bcat + (long)l * 2752512 + 655360;
  const int tid = threadIdx.x;
#pragma unroll
  for (int it = 0; it < 8; it++) {
    int d = it * 8 + (tid >> 5);
    int rr = (tid & 31) * 4;
    float4 v = *(const float4*)(src + ((long)n * 512 + d0 + d) * 128 + rr);
    tile[d][rr + 0] = f2bf(v.x);
    tile[d][rr + 1] = f2bf(v.y);
    tile[d][rr + 2] = f2bf(v.z);
    tile[d][rr + 3] = f2bf(v.w);
  }
  __syncthreads();
#pragma unroll
  for (int it = 0; it < 4; it++) {
    int rr = it * 32 + (tid >> 3);
    int dof = (tid & 7) * 8;
    short8 s;
#pragma unroll
    for (int j = 0; j < 8; j++) s[j] = (short)tile[dof + j][rr];
    *(short8*)(dst + ((long)n * 128 + rr) * 512 + d0 + dof) = s;
  }
}

__global__ __launch_bounds__(256) void embed_kernel(
    const int* __restrict__ ids, const float* __restrict__ tok,
    const float* __restrict__ pos, float* __restrict__ x)
{
  int i = blockIdx.x * 256 + threadIdx.x;
  int t = i >> 7, c = (i & 127) * 4;
  int sp = t & 1023;
  int id = ids[t];
  float4 a = *(const float4*)(tok + (long)id * 512 + c);
  float4 b = *(const float4*)(pos + (long)sp * 512 + c);
  float4 rr; rr.x=a.x+b.x; rr.y=a.y+b.y; rr.z=a.z+b.z; rr.w=a.w+b.w;
  *(float4*)(x + (long)t * 512 + c) = rr;
}

__global__ __launch_bounds__(256) void ln_kernel(
    const float* __restrict__ in, ushort* __restrict__ outh,
    const float* __restrict__ gam, const float* __restrict__ bet)
{
  int row = blockIdx.x * 4 + (threadIdx.x >> 6);
  int lane = threadIdx.x & 63;
  const float* p = in + (long)row * 512;
  float4 v0 = *(const float4*)(p + lane * 4);
  float4 v1 = *(const float4*)(p + 256 + lane * 4);
  float s = v0.x+v0.y+v0.z+v0.w + v1.x+v1.y+v1.z+v1.w;
#pragma unroll
  for (int o = 32; o; o >>= 1) s += __shfl_xor(s, o);
  float mean = s * (1.f/512.f);
  float d0=v0.x-mean, d1=v0.y-mean, d2=v0.z-mean, d3=v0.w-mean;
  float e0=v1.x-mean, e1=v1.y-mean, e2=v1.z-mean, e3=v1.w-mean;
  float qv = d0*d0+d1*d1+d2*d2+d3*d3 + e0*e0+e1*e1+e2*e2+e3*e3;
#pragma unroll
  for (int o = 32; o; o >>= 1) qv += __shfl_xor(qv, o);
  float inv = rsqrtf(qv * (1.f/512.f) + 1e-5f);
  float4 g0 = *(const float4*)(gam + lane*4);
  float4 g1 = *(const float4*)(gam + 256 + lane*4);
  float4 b0 = *(const float4*)(bet + lane*4);
  float4 b1 = *(const float4*)(bet + 256 + lane*4);
  short4v o0, o1;
  o0[0]=(short)f2bf(d0*inv*g0.x + b0.x); o0[1]=(short)f2bf(d1*inv*g0.y + b0.y);
  o0[2]=(short)f2bf(d2*inv*g0.z + b0.z); o0[3]=(short)f2bf(d3*inv*g0.w + b0.w);
  o1[0]=(short)f2bf(e0*inv*g1.x + b1.x); o1[1]=(short)f2bf(e1*inv*g1.y + b1.y);
  o1[2]=(short)f2bf(e2*inv*g1.z + b1.z); o1[3]=(short)f2bf(e3*inv*g1.w + b1.w);
  *(short4v*)(outh + (long)row*512 + lane*4) = o0;
  *(short4v*)(outh + (long)row*512 + 256 + lane*4) = o1;
}

// per (l,n): rec_sm=softmax(recipe), emb_sem(bf16) into Bcat rows 0-255, gate=const
__global__ __launch_bounds__(64) void precompute_kernel(
    const float* __restrict__ recipe, const float* __restrict__ basis_emb,
    const float* __restrict__ ctx_pat, float* __restrict__ rec_sm,
    ushort* __restrict__ Bcat, float* __restrict__ gate)
{
  int ln = blockIdx.x;
  int l = ln >> 8, n = ln & 255;
  int lane = threadIdx.x;
  const float* r = recipe + (long)ln * 32;
  float rv[32];
  float m = -1e30f;
#pragma unroll
  for (int j = 0; j < 32; j++) { rv[j] = r[j]; m = fmaxf(m, rv[j]); }
  float sum = 0.f;
#pragma unroll
  for (int j = 0; j < 32; j++) { rv[j] = expf(rv[j] - m); sum += rv[j]; }
  float inv = 1.f / sum;
#pragma unroll
  for (int j = 0; j < 32; j++) rv[j] *= inv;
  if (lane < 32) rec_sm[(long)ln * 32 + lane] = rv[lane];
  ushort* dst = Bcat + (long)l * 2752512 + (long)n * 512;
#pragma unroll
  for (int cc = 0; cc < 8; cc++) {
    int c = lane + cc * 64;
    float acc = 0.f;
#pragma unroll
    for (int j = 0; j < 32; j++) acc += rv[j] * basis_emb[j * 512 + c];
    dst[c] = f2bf(acc);
  }
  if (lane == 0) {
    float sh = 0.f;
#pragma unroll
    for (int h = 0; h < 8; h++) sh += ctx_pat[(long)ln * 8 + h];
    gate[ln] = 1.f / (1.f + expf(-sh * (1.f/1024.f)));
  }
}

// fused: top-8 + weight softmax + token_recipe + v_sem reduction. Wave per token.
__global__ __launch_bounds__(256) void topkvsem_kernel(
    const float* __restrict__ fin, const float* __restrict__ rec_sm_l,
    const ushort* __restrict__ XA, ushort* __restrict__ out)
{
  __shared__ float trs[4][32];
  int wv = threadIdx.x >> 6, lane = threadIdx.x & 63;
  int t = blockIdx.x * 4 + wv;
  const float* f = fin + (long)t * 256;
  float v0 = f[lane], v1 = f[lane+64], v2 = f[lane+128], v3 = f[lane+192];
  int i0 = lane, i1 = lane+64, i2 = lane+128, i3 = lane+192;
  float topv[8]; int topi[8];
#pragma unroll
  for (int it = 0; it < 8; it++) {
    float bm = v0; int bi = i0;
    if (v1 > bm || (v1 == bm && i1 < bi)) { bm = v1; bi = i1; }
    if (v2 > bm || (v2 == bm && i2 < bi)) { bm = v2; bi = i2; }
    if (v3 > bm || (v3 == bm && i3 < bi)) { bm = v3; bi = i3; }
#pragma unroll
    for (int o = 32; o; o >>= 1) {
      float om = __shfl_xor(bm, o);
      int oi = __shfl_xor(bi, o);
      if (om > bm || (om == bm && oi < bi)) { bm = om; bi = oi; }
    }
    topv[it] = bm; topi[it] = bi;
    if (i0 == bi) v0 = -1e30f;
    if (i1 == bi) v1 = -1e30f;
    if (i2 == bi) v2 = -1e30f;
    if (i3 == bi) v3 = -1e30f;
  }
  float w[8], wsum = 0.f;
#pragma unroll
  for (int k = 0; k < 8; k++) { w[k] = expf(topv[k] - topv[0]); wsum += w[k]; }
  float winv = 1.f / wsum;
  if (lane < 32) {
    float acc = 0.f;
#pragma unroll
    for (int k = 0; k < 8; k++)
      acc += (w[k] * winv) * rec_sm_l[(long)topi[k] * 32 + lane];
    trs[wv][lane] = acc;
  }
  __syncthreads();
  const ushort* xa = XA + (long)t * 4096;
  float a0 = 0.f, a1 = 0.f;
#pragma unroll
  for (int n = 0; n < 32; n++) {
    float wn = trs[wv][n];
    a0 += wn * bf2f(xa[n*128 + lane]);
    a1 += wn * bf2f(xa[n*128 + 64 + lane]);
  }
  out[(long)t * 128 + lane] = f2bf(a0);
  out[(long)t * 128 + 64 + lane] = f2bf(a1);
}

// ---------------------------------------------------------------------------
// host
// ---------------------------------------------------------------------------
extern "C" void kernel_launch(void* const* d_in, const int* in_sizes, int n_in,
                              void* d_out, int out_size, void* d_ws, size_t ws_size,
                              hipStream_t stream) {
  (void)in_sizes; (void)n_in; (void)out_size; (void)ws_size;
  const int*   ids       = (const int*)  d_in[0];
  const float* token_emb = (const float*)d_in[1];
  const float* pos_emb   = (const float*)d_in[2];
  const float* basis_A   = (const float*)d_in[3];
  const float* basis_emb = (const float*)d_in[4];
  const float* q_w  = (const float*)d_in[5];
  const float* q_b  = (const float*)d_in[6];
  const float* k_w  = (const float*)d_in[7];
  const float* k_b  = (const float*)d_in[8];
  const float* ao_w = (const float*)d_in[9];
  const float* ao_b = (const float*)d_in[10];
  const float* recipe  = (const float*)d_in[11];
  const float* ctx_pat = (const float*)d_in[12];
  const float* vout_w  = (const float*)d_in[13];
  const float* vout_b  = (const float*)d_in[14];
  const float* up_w    = (const float*)d_in[15];
  const float* up_b    = (const float*)d_in[16];
  const float* down_w  = (const float*)d_in[17];
  const float* down_b  = (const float*)d_in[18];
  const float* ln1_s = (const float*)d_in[19];
  const float* ln1_b = (const float*)d_in[20];
  const float* ln2_s = (const float*)d_in[21];
  const float* ln2_b = (const float*)d_in[22];
  const float* lnf_s = (const float*)d_in[23];
  const float* lnf_b = (const float*)d_in[24];
  float* out = (float*)d_out;

  // ws layout (~92 MB)
  float* ws    = (float*)d_ws;
  float* x     = ws;                 // [4096,512] f32
  float* finb  = x + 2097152;        // [4096,256] f32
  float* recsm = finb + 1048576;     // [4,256,32] f32
  float* gate  = recsm + 32768;      // [4,256] f32
  float* qkb   = gate + 1024;        // [4,1024] f32
  ushort* u = (ushort*)(qkb + 4096);
  ushort* nrmh    = u; u += 2097152;    // [4096,512]
  ushort* vsemh   = u; u += 524288;     // [4096,128]
  ushort* Bcat    = u; u += 11010048;   // [4][5376,512]
  ushort* aowh    = u; u += 1048576;    // [4,512,512]
  ushort* voutwh  = u; u += 262144;     // [4,512,128]
  ushort* upwh    = u; u += 4194304;    // [4,2048,512]
  ushort* downwh  = u; u += 4194304;    // [4,512,2048]
  ushort* tembh   = u; u += 16384000;   // [32000,512]

  // transients in d_out (524 MB; disjoint lifetimes, all overwritten by logits)
  ushort* XAb = (ushort*)out;              // [4096,4096] @ 0      (33.5 MB)
  ushort* HF  = (ushort*)out;              // [4096,2048] @ 0      (16.8 MB)
  ushort* qkh = (ushort*)out + 16777216;   // [4096,1024] @ 33.5MB
  ushort* vvh = (ushort*)out + 20971520;   // [4096,512]  @ 42MB
  ushort* aoh = (ushort*)out + 23068672;   // [4096,512]  @ 46MB

  // one-time conversions
  qkcvt_kernel<<<1024, 256, 0, stream>>>(q_w, k_w, Bcat);
  mkqkb_kernel<<<16, 256, 0, stream>>>(q_b, k_b, qkb);
  cvt_bf16<<<512, 256, 0, stream>>>(ao_w, aowh);
  cvt_bf16<<<128, 256, 0, stream>>>(vout_w, voutwh);
  cvt_bf16<<<2048, 256, 0, stream>>>(up_w, upwh);
  cvt_bf16<<<2048, 256, 0, stream>>>(down_w, downwh);
  cvt_bf16<<<8000, 256, 0, stream>>>(token_emb, tembh);
  transpose_basisA<<<dim3(32, 8, 4), 256, 0, stream>>>(basis_A, Bcat);
  embed_kernel<<<2048, 256, 0, stream>>>(ids, token_emb, pos_emb, x);
  precompute_kernel<<<1024, 64, 0, stream>>>(recipe, basis_emb, ctx_pat, recsm, Bcat, gate);

  for (int l = 0; l < 4; l++) {
    ln_kernel<<<1024, 256, 0, stream>>>(x, nrmh, ln1_s + l*512, ln1_b + l*512);
    // mega GEMM: fin | Q|K | xA
    megag1<<<dim3(42, 32), 256, 0, stream>>>(nrmh, Bcat + (long)l*2752512,
        finb, qkh, XAb, gate + l*256, qkb + l*1024);
    topkvsem_kernel<<<1024, 256, 0, stream>>>(finb, recsm + (long)l*8192, XAb, vsemh);
    // Vv = v_sem @ vout_w^T + vout_b
    gemmT<64,1><<<dim3(4, 64), 256, 0, stream>>>(vsemh, voutwh + (long)l*65536, vvh,
        vout_b + l*512, 128, 128, 128, 512, 1.f);
    flash_kernel<<<dim3(8, 32), 256, 0, stream>>>(qkh, vvh, aoh);
    // x += ao @ ao_w^T + ao_b
    gemmT<64,3><<<dim3(4, 64), 256, 0, stream>>>(aoh, aowh + (long)l*262144, x,
        ao_b + l*512, 512, 512, 512, 512, 1.f);
    // FFN
    ln_kernel<<<1024, 256, 0, stream>>>(x, nrmh, ln2_s + l*512, ln2_b + l*512);
    gemmT<128,2><<<dim3(16, 32), 256, 0, stream>>>(nrmh, upwh + (long)l*1048576, (void*)HF,
        up_b + l*2048, 512, 512, 512, 2048, 1.f);
    gemmT<64,3><<<dim3(4, 64), 256, 0, stream>>>(HF, downwh + (long)l*1048576, x,
        down_b + l*512, 2048, 2048, 2048, 512, 1.f);
  }

  ln_kernel<<<1024, 256, 0, stream>>>(x, nrmh, lnf_s, lnf_b);
  gemmT<128,4><<<dim3(250, 32), 256, 0, stream>>>(nrmh, tembh, out, nullptr,
      512, 512, 512, 32000, 1.f);
}

// Round 5
// 1131.556 us; speedup vs baseline: 2.2018x; 1.0011x over previous
//
#include <hip/hip_runtime.h>
#include <hip/hip_bf16.h>
#include <math.h>

typedef __attribute__((ext_vector_type(8))) short short8;
typedef __attribute__((ext_vector_type(4))) short short4v;
typedef __attribute__((ext_vector_type(8))) __bf16 bf16x8;
typedef __attribute__((ext_vector_type(4))) float f32x4;
typedef unsigned short ushort;

#define DEVI static __device__ __forceinline__

DEVI ushort f2bf(float f) {
  union { float f; unsigned u; } v; v.f = f;
  unsigned r = v.u + 0x7fffu + ((v.u >> 16) & 1u);
  return (ushort)(r >> 16);
}
DEVI float bf2f(ushort h) {
  union { unsigned u; float f; } v; v.u = (unsigned)h << 16; return v.f;
}
DEVI void gload16(const void* g, void* l) {
  __builtin_amdgcn_global_load_lds((const __attribute__((address_space(1))) void*)g,
                                   (__attribute__((address_space(3))) void*)l, 16, 0, 0);
}

// ---------------------------------------------------------------------------
// BMx128 bf16 MFMA GEMM, BK=64 (2 MFMA sub-steps per barrier pair):
// A [M,K] bf16, B [N,K] bf16 (B^T layout), 4 waves, global_load_lds staging,
// bijective XCD swizzle. BM in {64,128}.
// EPI: 1=bf16 store, 2=GELU->bf16, 3=f32 residual add, 4=f32 NT store
// ---------------------------------------------------------------------------
template<int BM, int EPI>
__global__ __launch_bounds__(256) void gemmT(
    const ushort* __restrict__ A, const ushort* __restrict__ B,
    void* __restrict__ Cv, const float* __restrict__ bias,
    int K, int lda, int ldb, int ldc, float scale)
{
  constexpr int BK = 64;
  constexpr int MF = BM / 32;       // m-fragments per wave
  constexpr int MH = BM / 2;        // rows per wave-half
  constexpr int ACH = BM * BK / 2048;   // 16B chunks per thread (A)
  constexpr int BCH = 128 * BK / 2048;  // = 4 (B)
  __shared__ ushort As[BM * BK];
  __shared__ ushort Bs[128 * BK];

  const int gx = gridDim.x;
  const int nwg = gx * gridDim.y;
  const int orig = blockIdx.y * gx + blockIdx.x;
  const int qq = nwg >> 3, rr = nwg & 7;
  const int xcd = orig & 7, sidx = orig >> 3;
  const int wg = (xcd < rr ? xcd * (qq + 1) : rr * (qq + 1) + (xcd - rr) * qq) + sidx;
  const int n0 = (wg % gx) * 128, m0 = (wg / gx) * BM;

  const int tid = threadIdx.x;
  const int lane = tid & 63, wv = tid >> 6;
  const int wm = wv >> 1, wn = wv & 1;
  const int l16 = lane & 15, lq = lane >> 4;

  f32x4 acc[MF][4];
#pragma unroll
  for (int i = 0; i < MF; i++)
#pragma unroll
    for (int j = 0; j < 4; j++) acc[i][j] = (f32x4){0.f, 0.f, 0.f, 0.f};

  const char* apS[ACH]; const char* bpS[BCH];
#pragma unroll
  for (int s = 0; s < ACH; s++) {
    int c = tid + 256 * s;
    apS[s] = (const char*)(A + (long)(m0 + (c >> 3)) * lda) + ((c & 7) << 4);
  }
#pragma unroll
  for (int s = 0; s < BCH; s++) {
    int c = tid + 256 * s;
    bpS[s] = (const char*)(B + (long)(n0 + (c >> 3)) * ldb) + ((c & 7) << 4);
  }

  for (int k0 = 0; k0 < K; k0 += BK) {
    const long kb = (long)k0 * 2;
#pragma unroll
    for (int s = 0; s < ACH; s++) gload16(apS[s] + kb, (char*)As + (tid + 256*s) * 16);
#pragma unroll
    for (int s = 0; s < BCH; s++) gload16(bpS[s] + kb, (char*)Bs + (tid + 256*s) * 16);
    __syncthreads();
#pragma unroll
    for (int ks = 0; ks < 2; ks++) {
      bf16x8 af[MF], bfr[4];
#pragma unroll
      for (int i = 0; i < MF; i++)
        af[i] = __builtin_bit_cast(bf16x8, *(const short8*)&As[(wm*MH + i*16 + l16)*BK + ks*32 + lq*8]);
#pragma unroll
      for (int j = 0; j < 4; j++)
        bfr[j] = __builtin_bit_cast(bf16x8, *(const short8*)&Bs[(wn*64 + j*16 + l16)*BK + ks*32 + lq*8]);
#pragma unroll
      for (int i = 0; i < MF; i++)
#pragma unroll
        for (int j = 0; j < 4; j++)
          acc[i][j] = __builtin_amdgcn_mfma_f32_16x16x32_bf16(af[i], bfr[j], acc[i][j], 0, 0, 0);
    }
    __syncthreads();
  }

  float* Cf = (float*)Cv;
  ushort* Ch = (ushort*)Cv;
#pragma unroll
  for (int i = 0; i < MF; i++) {
    const int row0 = m0 + wm*MH + i*16 + lq*4;
#pragma unroll
    for (int j = 0; j < 4; j++) {
      const int col = n0 + wn*64 + j*16 + l16;
      const float cb = bias ? bias[col] : 0.f;
#pragma unroll
      for (int t = 0; t < 4; t++) {
        float val = acc[i][j][t] * scale + cb;
        const long idx = (long)(row0 + t) * ldc + col;
        if (EPI == 1)      Ch[idx] = f2bf(val);
        else if (EPI == 2) { val = 0.5f * val * (1.f + erff(val * 0.70710678118654752f)); Ch[idx] = f2bf(val); }
        else if (EPI == 3) Cf[idx] += val;
        else               __builtin_nontemporal_store(val, Cf + idx);
      }
    }
  }
}

// ---------------------------------------------------------------------------
// Mega GEMM (BK=64): A=nrm [4096,512], B=Bcat[l] [5376,512]
// (rows: 256 emb_sem | 512 q_w | 512 k_w | 4096 basisAT). Grid (42,32).
// Epilogue routes by col: 0-255 -> finb f32*gate; 256-1279 -> qkh bf16+bias;
// 1280+ -> XAb bf16.
// ---------------------------------------------------------------------------
__global__ __launch_bounds__(256) void megag1(
    const ushort* __restrict__ A, const ushort* __restrict__ B,
    float* __restrict__ finb, ushort* __restrict__ qkh, ushort* __restrict__ XAb,
    const float* __restrict__ gate, const float* __restrict__ qkbias)
{
  constexpr int BK = 64;
  __shared__ ushort As[128 * BK];
  __shared__ ushort Bs[128 * BK];
  const int gx = gridDim.x;
  const int nwg = gx * gridDim.y;
  const int orig = blockIdx.y * gx + blockIdx.x;
  const int qq = nwg >> 3, rr = nwg & 7;
  const int xcd = orig & 7, sidx = orig >> 3;
  const int wg = (xcd < rr ? xcd * (qq + 1) : rr * (qq + 1) + (xcd - rr) * qq) + sidx;
  const int n0 = (wg % gx) * 128, m0 = (wg / gx) * 128;

  const int tid = threadIdx.x;
  const int lane = tid & 63, wv = tid >> 6;
  const int wm = wv >> 1, wn = wv & 1;
  const int l16 = lane & 15, lq = lane >> 4;

  f32x4 acc[4][4];
#pragma unroll
  for (int i = 0; i < 4; i++)
#pragma unroll
    for (int j = 0; j < 4; j++) acc[i][j] = (f32x4){0.f, 0.f, 0.f, 0.f};

  const char* apS[4]; const char* bpS[4];
#pragma unroll
  for (int s = 0; s < 4; s++) {
    int c = tid + 256 * s;
    apS[s] = (const char*)(A + (long)(m0 + (c >> 3)) * 512) + ((c & 7) << 4);
    bpS[s] = (const char*)(B + (long)(n0 + (c >> 3)) * 512) + ((c & 7) << 4);
  }

  for (int k0 = 0; k0 < 512; k0 += BK) {
    const long kb = (long)k0 * 2;
#pragma unroll
    for (int s = 0; s < 4; s++) {
      gload16(apS[s] + kb, (char*)As + (tid + 256*s) * 16);
      gload16(bpS[s] + kb, (char*)Bs + (tid + 256*s) * 16);
    }
    __syncthreads();
#pragma unroll
    for (int ks = 0; ks < 2; ks++) {
      bf16x8 af[4], bfr[4];
#pragma unroll
      for (int i = 0; i < 4; i++) {
        af[i]  = __builtin_bit_cast(bf16x8, *(const short8*)&As[(wm*64 + i*16 + l16)*BK + ks*32 + lq*8]);
        bfr[i] = __builtin_bit_cast(bf16x8, *(const short8*)&Bs[(wn*64 + i*16 + l16)*BK + ks*32 + lq*8]);
      }
#pragma unroll
      for (int i = 0; i < 4; i++)
#pragma unroll
        for (int j = 0; j < 4; j++)
          acc[i][j] = __builtin_amdgcn_mfma_f32_16x16x32_bf16(af[i], bfr[j], acc[i][j], 0, 0, 0);
    }
    __syncthreads();
  }

#pragma unroll
  for (int i = 0; i < 4; i++) {
    const int row0 = m0 + wm*64 + i*16 + lq*4;
#pragma unroll
    for (int j = 0; j < 4; j++) {
      const int col = n0 + wn*64 + j*16 + l16;
      if (col < 256) {
        const float g = gate[col];
#pragma unroll
        for (int t = 0; t < 4; t++) finb[(long)(row0 + t) * 256 + col] = acc[i][j][t] * g;
      } else if (col < 1280) {
        const int c = col - 256;
        const float bb = qkbias[c];
#pragma unroll
        for (int t = 0; t < 4; t++) qkh[(long)(row0 + t) * 1024 + c] = f2bf(acc[i][j][t] + bb);
      } else {
        const int c = col - 1280;
#pragma unroll
        for (int t = 0; t < 4; t++) XAb[(long)(row0 + t) * 4096 + c] = f2bf(acc[i][j][t]);
      }
    }
  }
}

// ---------------------------------------------------------------------------
// Fused causal flash attention with double-buffered K/V staging.
// qk: [4096,1024] bf16 (cols 0-511 Q, 512-1023 K). v: [4096,512]. o: [4096,512].
// Grid (8 pair, 32 bh), 256 threads. Pair p: q-tiles {p, 15-p} -> 17 kv-tiles.
// ---------------------------------------------------------------------------
__global__ __launch_bounds__(256) void flash_kernel(
    const ushort* __restrict__ qk, const ushort* __restrict__ v,
    ushort* __restrict__ o)
{
  __shared__ ushort Ks[2][4096];
  __shared__ ushort VTs[2][4096];
  __shared__ ushort Ps[4096];
  const int p = blockIdx.x, bh = blockIdx.y;
  const int b = bh >> 3, h = bh & 7;
  const int tid = threadIdx.x, lane = tid & 63, w = tid >> 6;
  const int l16 = lane & 15, lq = lane >> 4;
  const long tokbase = (long)b * 1024;
  const ushort* Qbase = qk + tokbase * 1024 + h * 64;
  const char*   Kbase = (const char*)(qk + tokbase * 1024 + 512 + h * 64);
  const ushort* Vbase = v + tokbase * 512 + h * 64;

  const int krow = tid >> 3, kcb = (tid & 7) << 4;
  const int vkv  = tid >> 2, vdb = (tid & 3) << 4;
  const int kswz = kcb ^ ((krow & 7) << 4);

#pragma unroll 1
  for (int half = 0; half < 2; half++) {
    const int qt = half ? (15 - p) : p;
    const int q0 = qt * 64;
    const int ntiles = qt + 1;

    const ushort* qrow = Qbase + (long)(q0 + w*16 + l16) * 1024;
    const bf16x8 qf0 = *(const bf16x8*)(qrow + lq*8);
    const bf16x8 qf1 = *(const bf16x8*)(qrow + 32 + lq*8);

    float m_[4] = {-1e30f, -1e30f, -1e30f, -1e30f};
    float l_[4] = {0.f, 0.f, 0.f, 0.f};
    f32x4 od[4];
#pragma unroll
    for (int dt = 0; dt < 4; dt++) od[dt] = (f32x4){0.f, 0.f, 0.f, 0.f};

    // prologue: stage tile 0 into buffer 0
    gload16(Kbase + (long)krow * 2048 + kswz, (char*)Ks[0] + tid * 16);
    gload16(Kbase + (long)(32 + krow) * 2048 + kswz, (char*)Ks[0] + 4096 + tid * 16);
    {
      const ushort* vr = Vbase + (long)vkv * 512 + vdb;
      short8 va = *(const short8*)vr;
      short8 vb = *(const short8*)(vr + 8);
#pragma unroll
      for (int j = 0; j < 8; j++) {
        int d1 = vdb + j, d2 = vdb + 8 + j;
        *(ushort*)((char*)VTs[0] + d1*128 + ((vkv*2) ^ ((d1 & 7) << 4))) = (ushort)va[j];
        *(ushort*)((char*)VTs[0] + d2*128 + ((vkv*2) ^ ((d2 & 7) << 4))) = (ushort)vb[j];
      }
    }
    __syncthreads();

    int cur = 0;
#pragma unroll 1
    for (int t = 0; t < ntiles; t++) {
      const bool hasn = (t + 1 < ntiles);
      short8 vaN, vbN;
      if (hasn) {
        const long n0g = (long)(t + 1) * 64;
        gload16(Kbase + (n0g + krow) * 2048 + kswz, (char*)Ks[cur ^ 1] + tid * 16);
        gload16(Kbase + (n0g + 32 + krow) * 2048 + kswz, (char*)Ks[cur ^ 1] + 4096 + tid * 16);
        const ushort* vr = Vbase + (n0g + vkv) * 512 + vdb;
        vaN = *(const short8*)vr;
        vbN = *(const short8*)(vr + 8);
      }

      // S = Q @ K^T
      f32x4 sa[4];
#pragma unroll
      for (int n = 0; n < 4; n++) sa[n] = (f32x4){0.f, 0.f, 0.f, 0.f};
#pragma unroll
      for (int ks = 0; ks < 2; ks++) {
        const bf16x8 qf = ks ? qf1 : qf0;
#pragma unroll
        for (int n = 0; n < 4; n++) {
          const int row = n*16 + l16;
          bf16x8 kf = *(const bf16x8*)((const char*)Ks[cur] + row*128 + ((ks*64 + lq*16) ^ ((row & 7) << 4)));
          sa[n] = __builtin_amdgcn_mfma_f32_16x16x32_bf16(qf, kf, sa[n], 0, 0, 0);
        }
      }

      const bool diag = (t == qt);
      float rowmax[4] = {-1e30f, -1e30f, -1e30f, -1e30f};
#pragma unroll
      for (int n = 0; n < 4; n++)
#pragma unroll
        for (int r = 0; r < 4; r++) {
          float sv = sa[n][r] * 0.125f;
          if (diag && (n*16 + l16 > w*16 + lq*4 + r)) sv = -1e30f;
          sa[n][r] = sv;
          rowmax[r] = fmaxf(rowmax[r], sv);
        }
#pragma unroll
      for (int r = 0; r < 4; r++)
#pragma unroll
        for (int off = 8; off; off >>= 1) rowmax[r] = fmaxf(rowmax[r], __shfl_xor(rowmax[r], off));

      float psum[4];
#pragma unroll
      for (int r = 0; r < 4; r++) {
        const float mn = fmaxf(m_[r], rowmax[r]);
        const float corr = __expf(m_[r] - mn);
        m_[r] = mn;
        l_[r] *= corr;
#pragma unroll
        for (int dt = 0; dt < 4; dt++) od[dt][r] *= corr;
        psum[r] = 0.f;
      }
#pragma unroll
      for (int n = 0; n < 4; n++)
#pragma unroll
        for (int r = 0; r < 4; r++) {
          const float pv = __expf(sa[n][r] - m_[r]);
          psum[r] += pv;
          const int prow = w*16 + lq*4 + r;
          *(ushort*)((char*)Ps + prow*128 + (((n*16 + l16)*2) ^ ((prow & 7) << 4))) = f2bf(pv);
        }
#pragma unroll
      for (int r = 0; r < 4; r++) {
#pragma unroll
        for (int off = 8; off; off >>= 1) psum[r] += __shfl_xor(psum[r], off);
        l_[r] += psum[r];
      }

      // O += P @ V  (P rows wave-private)
#pragma unroll
      for (int ks = 0; ks < 2; ks++) {
        const int prow = w*16 + l16;
        bf16x8 pf = *(const bf16x8*)((const char*)Ps + prow*128 + ((ks*64 + lq*16) ^ ((prow & 7) << 4)));
#pragma unroll
        for (int dt = 0; dt < 4; dt++) {
          const int vrow = dt*16 + l16;
          bf16x8 vf = *(const bf16x8*)((const char*)VTs[cur] + vrow*128 + ((ks*64 + lq*16) ^ ((vrow & 7) << 4)));
          od[dt] = __builtin_amdgcn_mfma_f32_16x16x32_bf16(pf, vf, od[dt], 0, 0, 0);
        }
      }

      if (hasn) {
#pragma unroll
        for (int j = 0; j < 8; j++) {
          int d1 = vdb + j, d2 = vdb + 8 + j;
          *(ushort*)((char*)VTs[cur ^ 1] + d1*128 + ((vkv*2) ^ ((d1 & 7) << 4))) = (ushort)vaN[j];
          *(ushort*)((char*)VTs[cur ^ 1] + d2*128 + ((vkv*2) ^ ((d2 & 7) << 4))) = (ushort)vbN[j];
        }
      }
      __syncthreads();
      cur ^= 1;
    }

#pragma unroll
    for (int r = 0; r < 4; r++) {
      const float inv = 1.f / l_[r];
      ushort* orow = o + (tokbase + q0 + w*16 + lq*4 + r) * 512 + h * 64 + l16;
#pragma unroll
      for (int dt = 0; dt < 4; dt++) orow[dt*16] = f2bf(od[dt][r] * inv);
    }
  }
}

// ---------------------------------------------------------------------------
// One-shot conversion kernel: all weight bf16 conversions + qk bias merge.
// Unit = 8 floats. Segments: qk(262144) ao(131072) vout(32768) up(524288)
// down(524288) temb(2048000) qkb(512). Total 3,523,072 units = 13762 blocks.
// ---------------------------------------------------------------------------
DEVI void cvt8(const float* s, ushort* d) {
  float4 u = *(const float4*)s, v = *(const float4*)(s + 4);
  short8 o;
  o[0]=(short)f2bf(u.x); o[1]=(short)f2bf(u.y); o[2]=(short)f2bf(u.z); o[3]=(short)f2bf(u.w);
  o[4]=(short)f2bf(v.x); o[5]=(short)f2bf(v.y); o[6]=(short)f2bf(v.z); o[7]=(short)f2bf(v.w);
  *(short8*)d = o;
}
__global__ __launch_bounds__(256) void cvt_all(
    const float* __restrict__ q_w, const float* __restrict__ k_w,
    const float* __restrict__ ao_w, const float* __restrict__ vout_w,
    const float* __restrict__ up_w, const float* __restrict__ down_w,
    const float* __restrict__ temb, const float* __restrict__ q_b,
    const float* __restrict__ k_b,
    ushort* __restrict__ Bcat, ushort* __restrict__ aowh, ushort* __restrict__ voutwh,
    ushort* __restrict__ upwh, ushort* __restrict__ downwh, ushort* __restrict__ tembh,
    float* __restrict__ qkb)
{
  long u = (long)blockIdx.x * 256 + threadIdx.x;
  if (u < 262144) {                    // q_w/k_w -> Bcat rows 256..1279 per layer
    long e = u * 8;
    int l = (int)(e >> 19);
    long rem = e & 524287;
    bool isk = rem >= 262144;
    long so = rem & 262143;
    cvt8((isk ? k_w : q_w) + (long)l * 262144 + so,
         Bcat + (long)l * 2752512 + 131072 + (isk ? 262144 : 0) + so);
    return;
  }
  u -= 262144;
  if (u < 131072) { cvt8(ao_w + u*8, aowh + u*8); return; }
  u -= 131072;
  if (u < 32768)  { cvt8(vout_w + u*8, voutwh + u*8); return; }
  u -= 32768;
  if (u < 524288) { cvt8(up_w + u*8, upwh + u*8); return; }
  u -= 524288;
  if (u < 524288) { cvt8(down_w + u*8, downwh + u*8); return; }
  u -= 524288;
  if (u < 2048000){ cvt8(temb + u*8, tembh + u*8); return; }
  u -= 2048000;
  {                                    // qkb interleave (f32 copy)
    long i8 = u * 8;
    int l = (int)(i8 >> 10), c = (int)(i8 & 1023);
    const float* src = (c < 512) ? (q_b + l*512 + c) : (k_b + l*512 + c - 512);
    float* dst = qkb + i8;
    *(float4*)dst = *(const float4*)src;
    *(float4*)(dst + 4) = *(const float4*)(src + 4);
  }
}

// basis_A [32][512][128] f32 -> Bcat[l] rows 1280.. as [32][128][512] bf16
__global__ __launch_bounds__(256) void transpose_basisA(
    const float* __restrict__ src, ushort* __restrict__ Bcat)
{
  __shared__ ushort tile[64][132];
  const int n = blockIdx.x;
  const int d0 = blockIdx.y * 64;
  const int l = blockIdx.z;
  ushort* dst = Bcat + (long)l * 2752512 + 655360;
  const int tid = threadIdx.x;
#pragma unroll
  for (int it = 0; it < 8; it++) {
    int d = it * 8 + (tid >> 5);
    int rr = (tid & 31) * 4;
    float4 v = *(const float4*)(src + ((long)n * 512 + d0 + d) * 128 + rr);
    tile[d][rr + 0] = f2bf(v.x);
    tile[d][rr + 1] = f2bf(v.y);
    tile[d][rr + 2] = f2bf(v.z);
    tile[d][rr + 3] = f2bf(v.w);
  }
  __syncthreads();
#pragma unroll
  for (int it = 0; it < 4; it++) {
    int rr = it * 32 + (tid >> 3);
    int dof = (tid & 7) * 8;
    short8 s;
#pragma unroll
    for (int j = 0; j < 8; j++) s[j] = (short)tile[dof + j][rr];
    *(short8*)(dst + ((long)n * 128 + rr) * 512 + d0 + dof) = s;
  }
}

// embed + LN1(layer0): x = tok[ids]+pos; nrmh = LN(x)
__global__ __launch_bounds__(256) void embed_ln(
    const int* __restrict__ ids, const float* __restrict__ tok,
    const float* __restrict__ pos, const float* __restrict__ gam,
    const float* __restrict__ bet, float* __restrict__ x, ushort* __restrict__ outh)
{
  int row = blockIdx.x * 4 + (threadIdx.x >> 6);
  int lane = threadIdx.x & 63;
  int id = ids[row], sp = row & 1023;
  const float* tp = tok + (long)id * 512;
  const float* pp = pos + (long)sp * 512;
  float4 v0 = *(const float4*)(tp + lane*4);
  float4 p0 = *(const float4*)(pp + lane*4);
  float4 v1 = *(const float4*)(tp + 256 + lane*4);
  float4 p1 = *(const float4*)(pp + 256 + lane*4);
  v0.x+=p0.x; v0.y+=p0.y; v0.z+=p0.z; v0.w+=p0.w;
  v1.x+=p1.x; v1.y+=p1.y; v1.z+=p1.z; v1.w+=p1.w;
  *(float4*)(x + (long)row*512 + lane*4) = v0;
  *(float4*)(x + (long)row*512 + 256 + lane*4) = v1;
  float s = v0.x+v0.y+v0.z+v0.w + v1.x+v1.y+v1.z+v1.w;
#pragma unroll
  for (int o = 32; o; o >>= 1) s += __shfl_xor(s, o);
  float mean = s * (1.f/512.f);
  float d0=v0.x-mean, d1=v0.y-mean, d2=v0.z-mean, d3=v0.w-mean;
  float e0=v1.x-mean, e1=v1.y-mean, e2=v1.z-mean, e3=v1.w-mean;
  float qv = d0*d0+d1*d1+d2*d2+d3*d3 + e0*e0+e1*e1+e2*e2+e3*e3;
#pragma unroll
  for (int o = 32; o; o >>= 1) qv += __shfl_xor(qv, o);
  float inv = rsqrtf(qv * (1.f/512.f) + 1e-5f);
  float4 g0 = *(const float4*)(gam + lane*4);
  float4 g1 = *(const float4*)(gam + 256 + lane*4);
  float4 b0 = *(const float4*)(bet + lane*4);
  float4 b1 = *(const float4*)(bet + 256 + lane*4);
  short4v o0, o1;
  o0[0]=(short)f2bf(d0*inv*g0.x + b0.x); o0[1]=(short)f2bf(d1*inv*g0.y + b0.y);
  o0[2]=(short)f2bf(d2*inv*g0.z + b0.z); o0[3]=(short)f2bf(d3*inv*g0.w + b0.w);
  o1[0]=(short)f2bf(e0*inv*g1.x + b1.x); o1[1]=(short)f2bf(e1*inv*g1.y + b1.y);
  o1[2]=(short)f2bf(e2*inv*g1.z + b1.z); o1[3]=(short)f2bf(e3*inv*g1.w + b1.w);
  *(short4v*)(outh + (long)row*512 + lane*4) = o0;
  *(short4v*)(outh + (long)row*512 + 256 + lane*4) = o1;
}

__global__ __launch_bounds__(256) void ln_kernel(
    const float* __restrict__ in, ushort* __restrict__ outh,
    const float* __restrict__ gam, const float* __restrict__ bet)
{
  int row = blockIdx.x * 4 + (threadIdx.x >> 6);
  int lane = threadIdx.x & 63;
  const float* p = in + (long)row * 512;
  float4 v0 = *(const float4*)(p + lane * 4);
  float4 v1 = *(const float4*)(p + 256 + lane * 4);
  float s = v0.x+v0.y+v0.z+v0.w + v1.x+v1.y+v1.z+v1.w;
#pragma unroll
  for (int o = 32; o; o >>= 1) s += __shfl_xor(s, o);
  float mean = s * (1.f/512.f);
  float d0=v0.x-mean, d1=v0.y-mean, d2=v0.z-mean, d3=v0.w-mean;
  float e0=v1.x-mean, e1=v1.y-mean, e2=v1.z-mean, e3=v1.w-mean;
  float qv = d0*d0+d1*d1+d2*d2+d3*d3 + e0*e0+e1*e1+e2*e2+e3*e3;
#pragma unroll
  for (int o = 32; o; o >>= 1) qv += __shfl_xor(qv, o);
  float inv = rsqrtf(qv * (1.f/512.f) + 1e-5f);
  float4 g0 = *(const float4*)(gam + lane*4);
  float4 g1 = *(const float4*)(gam + 256 + lane*4);
  float4 b0 = *(const float4*)(bet + lane*4);
  float4 b1 = *(const float4*)(bet + 256 + lane*4);
  short4v o0, o1;
  o0[0]=(short)f2bf(d0*inv*g0.x + b0.x); o0[1]=(short)f2bf(d1*inv*g0.y + b0.y);
  o0[2]=(short)f2bf(d2*inv*g0.z + b0.z); o0[3]=(short)f2bf(d3*inv*g0.w + b0.w);
  o1[0]=(short)f2bf(e0*inv*g1.x + b1.x); o1[1]=(short)f2bf(e1*inv*g1.y + b1.y);
  o1[2]=(short)f2bf(e2*inv*g1.z + b1.z); o1[3]=(short)f2bf(e3*inv*g1.w + b1.w);
  *(short4v*)(outh + (long)row*512 + lane*4) = o0;
  *(short4v*)(outh + (long)row*512 + 256 + lane*4) = o1;
}

// per (l,n): rec_sm=softmax(recipe), emb_sem(bf16) into Bcat rows 0-255, gate
__global__ __launch_bounds__(64) void precompute_kernel(
    const float* __restrict__ recipe, const float* __restrict__ basis_emb,
    const float* __restrict__ ctx_pat, float* __restrict__ rec_sm,
    ushort* __restrict__ Bcat, float* __restrict__ gate)
{
  int ln = blockIdx.x;
  int l = ln >> 8, n = ln & 255;
  int lane = threadIdx.x;
  const float* r = recipe + (long)ln * 32;
  float rv[32];
  float m = -1e30f;
#pragma unroll
  for (int j = 0; j < 32; j++) { rv[j] = r[j]; m = fmaxf(m, rv[j]); }
  float sum = 0.f;
#pragma unroll
  for (int j = 0; j < 32; j++) { rv[j] = expf(rv[j] - m); sum += rv[j]; }
  float inv = 1.f / sum;
#pragma unroll
  for (int j = 0; j < 32; j++) rv[j] *= inv;
  if (lane < 32) rec_sm[(long)ln * 32 + lane] = rv[lane];
  ushort* dst = Bcat + (long)l * 2752512 + (long)n * 512;
#pragma unroll
  for (int cc = 0; cc < 8; cc++) {
    int c = lane + cc * 64;
    float acc = 0.f;
#pragma unroll
    for (int j = 0; j < 32; j++) acc += rv[j] * basis_emb[j * 512 + c];
    dst[c] = f2bf(acc);
  }
  if (lane == 0) {
    float sh = 0.f;
#pragma unroll
    for (int h = 0; h < 8; h++) sh += ctx_pat[(long)ln * 8 + h];
    gate[ln] = 1.f / (1.f + expf(-sh * (1.f/1024.f)));
  }
}

// fused: top-8 + weight softmax + token_recipe + v_sem reduction. Wave/token.
__global__ __launch_bounds__(256) void topkvsem_kernel(
    const float* __restrict__ fin, const float* __restrict__ rec_sm_l,
    const ushort* __restrict__ XA, ushort* __restrict__ out)
{
  __shared__ float trs[4][32];
  int wv = threadIdx.x >> 6, lane = threadIdx.x & 63;
  int t = blockIdx.x * 4 + wv;
  const float* f = fin + (long)t * 256;
  float v0 = f[lane], v1 = f[lane+64], v2 = f[lane+128], v3 = f[lane+192];
  int i0 = lane, i1 = lane+64, i2 = lane+128, i3 = lane+192;
  float topv[8]; int topi[8];
#pragma unroll
  for (int it = 0; it < 8; it++) {
    float bm = v0; int bi = i0;
    if (v1 > bm || (v1 == bm && i1 < bi)) { bm = v1; bi = i1; }
    if (v2 > bm || (v2 == bm && i2 < bi)) { bm = v2; bi = i2; }
    if (v3 > bm || (v3 == bm && i3 < bi)) { bm = v3; bi = i3; }
#pragma unroll
    for (int o = 32; o; o >>= 1) {
      float om = __shfl_xor(bm, o);
      int oi = __shfl_xor(bi, o);
      if (om > bm || (om == bm && oi < bi)) { bm = om; bi = oi; }
    }
    topv[it] = bm; topi[it] = bi;
    if (i0 == bi) v0 = -1e30f;
    if (i1 == bi) v1 = -1e30f;
    if (i2 == bi) v2 = -1e30f;
    if (i3 == bi) v3 = -1e30f;
  }
  float w[8], wsum = 0.f;
#pragma unroll
  for (int k = 0; k < 8; k++) { w[k] = expf(topv[k] - topv[0]); wsum += w[k]; }
  float winv = 1.f / wsum;
  if (lane < 32) {
    float acc = 0.f;
#pragma unroll
    for (int k = 0; k < 8; k++)
      acc += (w[k] * winv) * rec_sm_l[(long)topi[k] * 32 + lane];
    trs[wv][lane] = acc;
  }
  __syncthreads();
  const ushort* xa = XA + (long)t * 4096;
  float a0 = 0.f, a1 = 0.f;
#pragma unroll
  for (int n = 0; n < 32; n++) {
    float wn = trs[wv][n];
    a0 += wn * bf2f(xa[n*128 + lane]);
    a1 += wn * bf2f(xa[n*128 + 64 + lane]);
  }
  out[(long)t * 128 + lane] = f2bf(a0);
  out[(long)t * 128 + 64 + lane] = f2bf(a1);
}

// ---------------------------------------------------------------------------
// host
// ---------------------------------------------------------------------------
extern "C" void kernel_launch(void* const* d_in, const int* in_sizes, int n_in,
                              void* d_out, int out_size, void* d_ws, size_t ws_size,
                              hipStream_t stream) {
  (void)in_sizes; (void)n_in; (void)out_size; (void)ws_size;
  const int*   ids       = (const int*)  d_in[0];
  const float* token_emb = (const float*)d_in[1];
  const float* pos_emb   = (const float*)d_in[2];
  const float* basis_A   = (const float*)d_in[3];
  const float* basis_emb = (const float*)d_in[4];
  const float* q_w  = (const float*)d_in[5];
  const float* q_b  = (const float*)d_in[6];
  const float* k_w  = (const float*)d_in[7];
  const float* k_b  = (const float*)d_in[8];
  const float* ao_w = (const float*)d_in[9];
  const float* ao_b = (const float*)d_in[10];
  const float* recipe  = (const float*)d_in[11];
  const float* ctx_pat = (const float*)d_in[12];
  const float* vout_w  = (const float*)d_in[13];
  const float* vout_b  = (const float*)d_in[14];
  const float* up_w    = (const float*)d_in[15];
  const float* up_b    = (const float*)d_in[16];
  const float* down_w  = (const float*)d_in[17];
  const float* down_b  = (const float*)d_in[18];
  const float* ln1_s = (const float*)d_in[19];
  const float* ln1_b = (const float*)d_in[20];
  const float* ln2_s = (const float*)d_in[21];
  const float* ln2_b = (const float*)d_in[22];
  const float* lnf_s = (const float*)d_in[23];
  const float* lnf_b = (const float*)d_in[24];
  float* out = (float*)d_out;

  // ws layout (~92 MB)
  float* ws    = (float*)d_ws;
  float* x     = ws;                 // [4096,512] f32
  float* finb  = x + 2097152;        // [4096,256] f32
  float* recsm = finb + 1048576;     // [4,256,32] f32
  float* gate  = recsm + 32768;      // [4,256] f32
  float* qkb   = gate + 1024;        // [4,1024] f32
  ushort* u = (ushort*)(qkb + 4096);
  ushort* nrmh    = u; u += 2097152;    // [4096,512]
  ushort* vsemh   = u; u += 524288;     // [4096,128]
  ushort* Bcat    = u; u += 11010048;   // [4][5376,512]
  ushort* aowh    = u; u += 1048576;    // [4,512,512]
  ushort* voutwh  = u; u += 262144;     // [4,512,128]
  ushort* upwh    = u; u += 4194304;    // [4,2048,512]
  ushort* downwh  = u; u += 4194304;    // [4,512,2048]
  ushort* tembh   = u; u += 16384000;   // [32000,512]

  // transients in d_out (disjoint lifetimes; all overwritten by logits)
  ushort* XAb = (ushort*)out;              // [4096,4096] @ 0
  ushort* HF  = (ushort*)out;              // [4096,2048] @ 0
  ushort* qkh = (ushort*)out + 16777216;   // [4096,1024]
  ushort* vvh = (ushort*)out + 20971520;   // [4096,512]
  ushort* aoh = (ushort*)out + 23068672;   // [4096,512]

  // startup (4 dispatches)
  cvt_all<<<13762, 256, 0, stream>>>(q_w, k_w, ao_w, vout_w, up_w, down_w,
      token_emb, q_b, k_b, Bcat, aowh, voutwh, upwh, downwh, tembh, qkb);
  transpose_basisA<<<dim3(32, 8, 4), 256, 0, stream>>>(basis_A, Bcat);
  precompute_kernel<<<1024, 64, 0, stream>>>(recipe, basis_emb, ctx_pat, recsm, Bcat, gate);
  embed_ln<<<1024, 256, 0, stream>>>(ids, token_emb, pos_emb, ln1_s, ln1_b, x, nrmh);

  for (int l = 0; l < 4; l++) {
    if (l) ln_kernel<<<1024, 256, 0, stream>>>(x, nrmh, ln1_s + l*512, ln1_b + l*512);
    // mega GEMM: fin | Q|K | xA
    megag1<<<dim3(42, 32), 256, 0, stream>>>(nrmh, Bcat + (long)l*2752512,
        finb, qkh, XAb, gate + l*256, qkb + l*1024);
    topkvsem_kernel<<<1024, 256, 0, stream>>>(finb, recsm + (long)l*8192, XAb, vsemh);
    // Vv = v_sem @ vout_w^T + vout_b
    gemmT<64,1><<<dim3(4, 64), 256, 0, stream>>>(vsemh, voutwh + (long)l*65536, vvh,
        vout_b + l*512, 128, 128, 128, 512, 1.f);
    flash_kernel<<<dim3(8, 32), 256, 0, stream>>>(qkh, vvh, aoh);
    // x += ao @ ao_w^T + ao_b
    gemmT<64,3><<<dim3(4, 64), 256, 0, stream>>>(aoh, aowh + (long)l*262144, x,
        ao_b + l*512, 512, 512, 512, 512, 1.f);
    // FFN
    ln_kernel<<<1024, 256, 0, stream>>>(x, nrmh, ln2_s + l*512, ln2_b + l*512);
    gemmT<128,2><<<dim3(16, 32), 256, 0, stream>>>(nrmh, upwh + (long)l*1048576, (void*)HF,
        up_b + l*2048, 512, 512, 512, 2048, 1.f);
    gemmT<64,3><<<dim3(4, 64), 256, 0, stream>>>(HF, downwh + (long)l*1048576, x,
        down_b + l*512, 2048, 2048, 2048, 512, 1.f);
  }

  ln_kernel<<<1024, 256, 0, stream>>>(x, nrmh, lnf_s, lnf_b);
  gemmT<128,4><<<dim3(250, 32), 256, 0, stream>>>(nrmh, tembh, out, nullptr,
      512, 512, 512, 32000, 1.f);
}